// Round 1
// baseline (2106.571 us; speedup 1.0000x reference)
//
#include <hip/hip_runtime.h>

// ---------------- constants / output layout (floats) ----------------
#define OFF1_OFF 0
#define OFF2_OFF 4718592
#define OFF3_OFF 5898240
#define R11_OFF  6193152      // 4*64*256*256 = 16,777,216 = 4096^2 (P scratch)
#define R21_OFF  22970368     // 4*128*128*128 = 8,388,608 (n1+n2 scratch)
#define R31_OFF  31358976     // 4*256*64*64 = 4,194,304

// ---------------- per-pixel channel L2 normalize --------------------
// in/out layout (b,c,64,64); block = 256 thr (4 cgroups x 64 x); grid (64 h, 4 b, 2 tensor)
__global__ __launch_bounds__(256)
void k_normalize(const float* __restrict__ f1, const float* __restrict__ f2,
                 float* __restrict__ n1, float* __restrict__ n2) {
  __shared__ float red[256];
  __shared__ float inv[64];
  const int t = threadIdx.x, x = t & 63, cg = t >> 6;
  const int h = blockIdx.x, b = blockIdx.y;
  const float* in = blockIdx.z ? f2 : f1;
  float*       op = blockIdx.z ? n2 : n1;
  const size_t base = (size_t)b * 256 * 4096 + (size_t)h * 64 + x;
  float s = 0.f;
  #pragma unroll 8
  for (int ci = 0; ci < 64; ++ci) {
    float v = in[base + (size_t)(cg * 64 + ci) * 4096];
    s = fmaf(v, v, s);
  }
  red[t] = s;
  __syncthreads();
  if (t < 64) {
    float tot = red[t] + red[64 + t] + red[128 + t] + red[192 + t];
    inv[t] = 1.0f / fmaxf(sqrtf(tot), 1e-12f);
  }
  __syncthreads();
  const float iv = inv[x];
  #pragma unroll 8
  for (int ci = 0; ci < 64; ++ci) {
    size_t idx = base + (size_t)(cg * 64 + ci) * 4096;
    op[idx] = in[idx] * iv;
  }
}

// ---------------- weight transpose: wT[k][oc] = w[oc][k] -------------
__global__ void k_wt(const float* __restrict__ w, float* __restrict__ wT,
                     int Cout, int K) {
  int gid = blockIdx.x * 256 + threadIdx.x;
  if (gid >= Cout * K) return;
  int oc = gid % Cout, k = gid / Cout;
  wT[gid] = w[oc * K + k];
}

// ---------------- pixel-correlation GEMM: P = A^T B ------------------
// A,B: [256][4096] (k-major), P: [4096][4096]. 128x128 tile, 8x8/thread.
__global__ __launch_bounds__(256)
void k_pgemm(const float* __restrict__ A, const float* __restrict__ Bm,
             float* __restrict__ P) {
  __shared__ __align__(16) float As[16 * 128];
  __shared__ __align__(16) float Bs[16 * 128];
  const int t = threadIdx.x;
  const int u0 = blockIdx.y * 128, v0 = blockIdx.x * 128;
  const int tx = t & 15, ty = t >> 4;
  float acc[8][8];
  #pragma unroll
  for (int r = 0; r < 8; ++r)
    #pragma unroll
    for (int s = 0; s < 8; ++s) acc[r][s] = 0.f;

  #pragma unroll 1
  for (int kt = 0; kt < 16; ++kt) {
    __syncthreads();
    #pragma unroll
    for (int i = 0; i < 8; ++i) {
      int e = t + i * 256;
      int k = e >> 7, m = e & 127;
      As[k * 128 + m] = A[(size_t)(kt * 16 + k) * 4096 + u0 + m];
      Bs[k * 128 + m] = Bm[(size_t)(kt * 16 + k) * 4096 + v0 + m];
    }
    __syncthreads();
    #pragma unroll
    for (int kk = 0; kk < 16; ++kk) {
      const float4 a0 = *(const float4*)(As + kk * 128 + ty * 8);
      const float4 a1 = *(const float4*)(As + kk * 128 + ty * 8 + 4);
      const float4 b0 = *(const float4*)(Bs + kk * 128 + tx * 8);
      const float4 b1 = *(const float4*)(Bs + kk * 128 + tx * 8 + 4);
      const float av[8] = {a0.x, a0.y, a0.z, a0.w, a1.x, a1.y, a1.z, a1.w};
      const float bv[8] = {b0.x, b0.y, b0.z, b0.w, b1.x, b1.y, b1.z, b1.w};
      #pragma unroll
      for (int r = 0; r < 8; ++r)
        #pragma unroll
        for (int s = 0; s < 8; ++s)
          acc[r][s] = fmaf(av[r], bv[s], acc[r][s]);
    }
  }
  #pragma unroll
  for (int r = 0; r < 8; ++r) {
    size_t row = (size_t)(u0 + ty * 8 + r) * 4096 + v0 + tx * 8;
    float4 lo = {acc[r][0], acc[r][1], acc[r][2], acc[r][3]};
    float4 hi = {acc[r][4], acc[r][5], acc[r][6], acc[r][7]};
    *(float4*)(P + row) = lo;
    *(float4*)(P + row + 4) = hi;
  }
}

// ---------------- 9-tap diagonal sum + per-row partial argmax --------
// grid (qy=62, py=62); LDS holds P[(py+di)*64+ux][(qy+di)*64+vx], di=0..2, pad 65.
__global__ __launch_bounds__(256)
void k_corr(const float* __restrict__ P, float* __restrict__ pv,
            int* __restrict__ pi) {
  __shared__ float lds[3 * 64 * 65];   // 12480 floats
  __shared__ float rv[256];
  __shared__ int   ri[256];
  const int t = threadIdx.x;
  const int qy = blockIdx.x, py = blockIdx.y;
  #pragma unroll
  for (int i = 0; i < 12; ++i) {
    int e = t + i * 256;                 // float4 index 0..3071
    int blk = e >> 10, rem = e & 1023;
    int ux = rem >> 4, v4 = (rem & 15) << 2;
    const float4 src = *(const float4*)(
        P + ((size_t)((py + blk) * 64 + ux)) * 4096 + (qy + blk) * 64 + v4);
    float* d = lds + blk * 4160 + ux * 65 + v4;
    d[0] = src.x; d[1] = src.y; d[2] = src.z; d[3] = src.w;
  }
  __syncthreads();
  const int px = t & 63, qg = t >> 6;
  float bv = -3.4e38f; int bq = 0;
  if (px < 62) {
    const int q0 = qg * 16;
    const int nq = (qg < 3) ? 16 : 14;
    const float* base = lds + px * 65 + q0;
    for (int l = 0; l < nq; ++l) {
      float s = 0.f;
      #pragma unroll
      for (int di = 0; di < 3; ++di)
        #pragma unroll
        for (int dj = 0; dj < 3; ++dj)
          s += base[di * 4160 + dj * 66 + l];
      if (s > bv) { bv = s; bq = q0 + l; }
    }
  }
  rv[t] = bv; ri[t] = bq;
  __syncthreads();
  if (t < 62) {
    float v = rv[t]; int q = ri[t];
    #pragma unroll
    for (int g = 1; g < 4; ++g) {
      float v2 = rv[g * 64 + t];
      if (v2 > v) { v = v2; q = ri[g * 64 + t]; }
    }
    const int n = py * 62 + t;
    pv[(size_t)n * 62 + qy] = v;
    pi[(size_t)n * 62 + qy] = qy * 62 + q;
  }
}

// ---------------- final argmax over the 62 qy partials ---------------
__global__ void k_argmax(const float* __restrict__ pv, const int* __restrict__ pi,
                         int* __restrict__ idxf) {
  int tid = blockIdx.x * 256 + threadIdx.x;
  if (tid >= 4 * 3844) return;
  const float* v = pv + (size_t)tid * 62;
  const int*  ii = pi + (size_t)tid * 62;
  float bv = v[0]; int bi = ii[0];
  for (int q = 1; q < 62; ++q) {
    float x = v[q];
    if (x > bv) { bv = x; bi = ii[q]; }
  }
  idxf[tid] = bi;
}

// ---------------- flow pyramid + 9 shifts ----------------------------
// out element ((b*9+s)*Ho + y)*Ho + x, float2 (fw,fh). sc = 1<<lg.
__global__ void k_flow(const int* __restrict__ idxf, float* __restrict__ out,
                       int Ho, int lg) {
  int gid = blockIdx.x * 256 + threadIdx.x;
  const int total = 4 * 9 * Ho * Ho;
  if (gid >= total) return;
  const int x = gid % Ho;
  const int y = (gid / Ho) % Ho;
  const int s = (gid / (Ho * Ho)) % 9;
  const int b = gid / (Ho * Ho * 9);
  const int i = s / 3, j = s % 3;
  const int sc = 1 << lg;
  const int yy = y - i * sc, xx = x - j * sc;
  float fw = 0.f, fh = 0.f;
  if (yy >= 0 && xx >= 0) {
    const int r = yy >> lg, c = xx >> lg;
    if (r < 62 && c < 62) {
      const int id = idxf[b * 3844 + r * 62 + c];
      fw = (float)((id % 62 - c) * sc);
      fh = (float)((id / 62 - r) * sc);
    }
  }
  float2 o = {fw, fh};
  *(float2*)(out + (size_t)gid * 2) = o;
}

// ---------------- conv1_1: 3->64 with fused input normalization ------
__global__ __launch_bounds__(256)
void k_conv11(const float* __restrict__ img, const float* __restrict__ w,
              const float* __restrict__ bias, float* __restrict__ out) {
  __shared__ float wl[1728];
  __shared__ float bl[64];
  const int t = threadIdx.x;
  for (int i = t; i < 1728; i += 256) wl[i] = w[i];
  if (t < 64) bl[t] = bias[t];
  __syncthreads();
  const int x = t;
  const int y = blockIdx.x, b = blockIdx.y;
  const float mean[3] = {0.485f, 0.456f, 0.406f};
  const float stdv[3] = {0.229f, 0.224f, 0.225f};
  float v[27];
  #pragma unroll
  for (int c = 0; c < 3; ++c)
    #pragma unroll
    for (int dy = 0; dy < 3; ++dy)
      #pragma unroll
      for (int dx = 0; dx < 3; ++dx) {
        int iy = y + dy - 1, ix = x + dx - 1;
        float val = 0.f;
        if (iy >= 0 && iy < 256 && ix >= 0 && ix < 256)
          val = (img[((size_t)(b * 3 + c) * 256 + iy) * 256 + ix] - mean[c]) / stdv[c];
        v[c * 9 + dy * 3 + dx] = val;
      }
  #pragma unroll 4
  for (int oc = 0; oc < 64; ++oc) {
    float a = bl[oc];
    #pragma unroll
    for (int k = 0; k < 27; ++k) a = fmaf(wl[oc * 27 + k], v[k], a);
    out[((size_t)(b * 64 + oc) * 256 + y) * 256 + x] = fmaxf(a, 0.f);
  }
}

// ---------------- generic 3x3 conv (implicit GEMM) -------------------
// tile: M=128 (2 rows x 64 x) spatial, N=64 oc, BK=36 (4 ci x 9 taps).
// bias+relu fused; POOL fuses 2x2 maxpool (writes H/2 x W/2).
template <int CIN, bool POOL>
__global__ __launch_bounds__(256)
void k_conv(const float* __restrict__ in, const float* __restrict__ wT,
            const float* __restrict__ bias, float* __restrict__ out,
            int H, int W, int Cout) {
  __shared__ __align__(16) float smem[128 * 65];  // staging 6912 < 8320 epilogue
  float* As = smem;            // [36][128]
  float* Bs = smem + 36 * 128; // [36][64]
  const int t = threadIdx.x;
  const int xtiles = W >> 6;
  const int xt = blockIdx.x % xtiles;
  const int yp = blockIdx.x / xtiles;
  const int x0 = xt << 6, y0 = yp << 1;
  const int ocb = blockIdx.y << 6;
  const int b = blockIdx.z;
  const float* inb = in + (size_t)b * CIN * H * W;
  const int tx = t & 15, ty = t >> 4;
  float acc[8][4];
  #pragma unroll
  for (int r = 0; r < 8; ++r)
    #pragma unroll
    for (int j = 0; j < 4; ++j) acc[r][j] = 0.f;

  #pragma unroll 1
  for (int cg = 0; cg < CIN / 4; ++cg) {
    __syncthreads();
    #pragma unroll
    for (int i = 0; i < 18; ++i) {
      int e = t + i * 256;
      int kk = e >> 7, sp = e & 127;
      int ci = (cg << 2) + kk / 9;
      int rr = kk % 9;
      int iy = y0 + (sp >> 6) + rr / 3 - 1;
      int ix = x0 + (sp & 63) + rr % 3 - 1;
      float v = 0.f;
      if (iy >= 0 && iy < H && ix >= 0 && ix < W)
        v = inb[((size_t)ci * H + iy) * W + ix];
      As[kk * 128 + sp] = v;
    }
    #pragma unroll
    for (int i = 0; i < 9; ++i) {
      int e = t + i * 256;
      int kk = e >> 6, oc = e & 63;
      Bs[kk * 64 + oc] = wT[(cg * 36 + kk) * Cout + ocb + oc];
    }
    __syncthreads();
    #pragma unroll
    for (int kk = 0; kk < 36; ++kk) {
      const float4 a0 = *(const float4*)(As + kk * 128 + ty * 8);
      const float4 a1 = *(const float4*)(As + kk * 128 + ty * 8 + 4);
      const float4 bb = *(const float4*)(Bs + kk * 64 + tx * 4);
      const float av[8] = {a0.x, a0.y, a0.z, a0.w, a1.x, a1.y, a1.z, a1.w};
      const float bw[4] = {bb.x, bb.y, bb.z, bb.w};
      #pragma unroll
      for (int r = 0; r < 8; ++r)
        #pragma unroll
        for (int j = 0; j < 4; ++j)
          acc[r][j] = fmaf(av[r], bw[j], acc[r][j]);
    }
  }
  __syncthreads();
  // bias + relu into LDS transpose buffer [sp][oc] (stride 65)
  #pragma unroll
  for (int r = 0; r < 8; ++r)
    #pragma unroll
    for (int j = 0; j < 4; ++j) {
      float v = acc[r][j] + bias[ocb + tx * 4 + j];
      smem[(ty * 8 + r) * 65 + tx * 4 + j] = fmaxf(v, 0.f);
    }
  __syncthreads();
  if (POOL) {
    const int Ho = H >> 1, Wo = W >> 1;
    #pragma unroll
    for (int i = 0; i < 8; ++i) {
      int e = t + i * 256;
      int xp = e & 31, oc = e >> 5;
      float v0 = smem[(xp * 2) * 65 + oc];
      float v1 = smem[(xp * 2 + 1) * 65 + oc];
      float v2 = smem[(64 + xp * 2) * 65 + oc];
      float v3 = smem[(64 + xp * 2 + 1) * 65 + oc];
      out[((size_t)(b * Cout + ocb + oc) * Ho + yp) * Wo + (x0 >> 1) + xp] =
          fmaxf(fmaxf(v0, v1), fmaxf(v2, v3));
    }
  } else {
    #pragma unroll
    for (int i = 0; i < 32; ++i) {
      int e = t + i * 256;
      int oc = e >> 7, sp = e & 127;
      out[((size_t)(b * Cout + ocb + oc) * H + y0 + (sp >> 6)) * W + x0 + (sp & 63)] =
          smem[sp * 65 + oc];
    }
  }
}

// ---------------------------------------------------------------------
extern "C" void kernel_launch(void* const* d_in, const int* in_sizes, int n_in,
                              void* d_out, int out_size, void* d_ws, size_t ws_size,
                              hipStream_t stream) {
  const float* df1 = (const float*)d_in[0];
  const float* df2 = (const float*)d_in[1];
  const float* img = (const float*)d_in[2];
  const float* w11 = (const float*)d_in[3];
  const float* b11 = (const float*)d_in[4];
  const float* w12 = (const float*)d_in[5];
  const float* b12 = (const float*)d_in[6];
  const float* w21 = (const float*)d_in[7];
  const float* b21 = (const float*)d_in[8];
  const float* w22 = (const float*)d_in[9];
  const float* b22 = (const float*)d_in[10];
  const float* w31 = (const float*)d_in[11];
  const float* b31 = (const float*)d_in[12];
  float* out = (float*)d_out;

  // ws scratch (~2.3 MB): final argmax indices + transposed conv weights
  int*   idxf = (int*)d_ws;
  float* w12T = (float*)d_ws + 15376;
  float* w21T = w12T + 576 * 64;
  float* w22T = w21T + 576 * 128;
  float* w31T = w22T + 1152 * 128;

  // big scratch overlaid on d_out regions (dead before real outputs land):
  float* n1 = out + R21_OFF;                 // normalized fin, 4,194,304
  float* n2 = n1 + 4194304;                  // normalized fref
  float* P  = out + R11_OFF;                 // 4096^2 pixel correlations
  float* pv = out + OFF1_OFF;                // partial max vals 4*3844*62
  int*   pi = (int*)(out + OFF1_OFF + 953312);
  float* pool1 = out + OFF1_OFF;             // after pv/pi dead
  float* pool2 = out + OFF1_OFF;             // after pool1 dead

  k_normalize<<<dim3(64, 4, 2), 256, 0, stream>>>(df1, df2, n1, n2);
  k_wt<<<(576 * 64 + 255) / 256, 256, 0, stream>>>(w12, w12T, 64, 576);
  k_wt<<<(576 * 128 + 255) / 256, 256, 0, stream>>>(w21, w21T, 128, 576);
  k_wt<<<(1152 * 128 + 255) / 256, 256, 0, stream>>>(w22, w22T, 128, 1152);
  k_wt<<<(1152 * 256 + 255) / 256, 256, 0, stream>>>(w31, w31T, 256, 1152);

  for (int b = 0; b < 4; ++b) {
    k_pgemm<<<dim3(32, 32), 256, 0, stream>>>(n1 + (size_t)b * 1048576,
                                              n2 + (size_t)b * 1048576, P);
    k_corr<<<dim3(62, 62), 256, 0, stream>>>(P, pv + (size_t)b * 238328,
                                             pi + (size_t)b * 238328);
  }
  k_argmax<<<(15376 + 255) / 256, 256, 0, stream>>>(pv, pi, idxf);

  // VGG chain (runs after correspondence so the d_out overlays are dead)
  k_conv11<<<dim3(256, 4), 256, 0, stream>>>(img, w11, b11, out + R11_OFF);
  k_conv<64, true ><<<dim3(4 * 128, 1, 4), 256, 0, stream>>>(out + R11_OFF, w12T, b12, pool1, 256, 256, 64);
  k_conv<64, false><<<dim3(2 * 64, 2, 4), 256, 0, stream>>>(pool1, w21T, b21, out + R21_OFF, 128, 128, 128);
  k_conv<128, true ><<<dim3(2 * 64, 2, 4), 256, 0, stream>>>(out + R21_OFF, w22T, b22, pool2, 128, 128, 128);
  k_conv<128, false><<<dim3(1 * 32, 4, 4), 256, 0, stream>>>(pool2, w31T, b31, out + R31_OFF, 64, 64, 256);

  // offset pyramids last (they overwrite the off1 scratch region)
  k_flow<<<(4 * 9 * 256 * 256 + 255) / 256, 256, 0, stream>>>(idxf, out + OFF1_OFF, 256, 2);
  k_flow<<<(4 * 9 * 128 * 128 + 255) / 256, 256, 0, stream>>>(idxf, out + OFF2_OFF, 128, 1);
  k_flow<<<(4 * 9 * 64 * 64 + 255) / 256, 256, 0, stream>>>(idxf, out + OFF3_OFF, 64, 0);
}

// Round 2
// 1223.954 us; speedup vs baseline: 1.7211x; 1.7211x over previous
//
#include <hip/hip_runtime.h>

typedef __attribute__((ext_vector_type(4))) float f32x4;
typedef __attribute__((ext_vector_type(8))) short s16x8;

// ---------------- output layout (float element offsets) ----------------
#define OFF1_OFF 0
#define OFF2_OFF 4718592
#define OFF3_OFF 5898240
#define R11_OFF  6193152      // 4*64*256*256 = 16,777,216 = 4096^2 (P scratch)
#define R21_OFF  22970368     // 4*128*128*128 = 8,388,608 (n1+n2 scratch)
#define R31_OFF  31358976     // 4*256*64*64 = 4,194,304

__device__ __forceinline__ ushort f2bf(float x) {
  union { float f; uint u; } c; c.f = x;
  uint r = c.u + 0x7FFFu + ((c.u >> 16) & 1u);
  return (ushort)(r >> 16);
}
__device__ __forceinline__ float bfval(ushort h) {
  union { uint u; float f; } c; c.u = ((uint)h) << 16;
  return c.f;
}

// ---------------- per-pixel channel L2 normalize --------------------
__global__ __launch_bounds__(256)
void k_normalize(const float* __restrict__ f1, const float* __restrict__ f2,
                 float* __restrict__ n1, float* __restrict__ n2) {
  __shared__ float red[256];
  __shared__ float inv[64];
  const int t = threadIdx.x, x = t & 63, cg = t >> 6;
  const int h = blockIdx.x, b = blockIdx.y;
  const float* in = blockIdx.z ? f2 : f1;
  float*       op = blockIdx.z ? n2 : n1;
  const size_t base = (size_t)b * 256 * 4096 + (size_t)h * 64 + x;
  float s = 0.f;
  #pragma unroll 8
  for (int ci = 0; ci < 64; ++ci) {
    float v = in[base + (size_t)(cg * 64 + ci) * 4096];
    s = fmaf(v, v, s);
  }
  red[t] = s;
  __syncthreads();
  if (t < 64) {
    float tot = red[t] + red[64 + t] + red[128 + t] + red[192 + t];
    inv[t] = 1.0f / fmaxf(sqrtf(tot), 1e-12f);
  }
  __syncthreads();
  const float iv = inv[x];
  #pragma unroll 8
  for (int ci = 0; ci < 64; ++ci) {
    size_t idx = base + (size_t)(cg * 64 + ci) * 4096;
    op[idx] = in[idx] * iv;
  }
}

// ---------------- pixel-correlation GEMM: P = A^T B ------------------
__global__ __launch_bounds__(256)
void k_pgemm(const float* __restrict__ A, const float* __restrict__ Bm,
             float* __restrict__ P) {
  __shared__ __align__(16) float As[16 * 128];
  __shared__ __align__(16) float Bs[16 * 128];
  const int t = threadIdx.x;
  const int u0 = blockIdx.y * 128, v0 = blockIdx.x * 128;
  const int tx = t & 15, ty = t >> 4;
  float acc[8][8];
  #pragma unroll
  for (int r = 0; r < 8; ++r)
    #pragma unroll
    for (int s = 0; s < 8; ++s) acc[r][s] = 0.f;

  #pragma unroll 1
  for (int kt = 0; kt < 16; ++kt) {
    __syncthreads();
    #pragma unroll
    for (int i = 0; i < 8; ++i) {
      int e = t + i * 256;
      int k = e >> 7, m = e & 127;
      As[k * 128 + m] = A[(size_t)(kt * 16 + k) * 4096 + u0 + m];
      Bs[k * 128 + m] = Bm[(size_t)(kt * 16 + k) * 4096 + v0 + m];
    }
    __syncthreads();
    #pragma unroll
    for (int kk = 0; kk < 16; ++kk) {
      const float4 a0 = *(const float4*)(As + kk * 128 + ty * 8);
      const float4 a1 = *(const float4*)(As + kk * 128 + ty * 8 + 4);
      const float4 b0 = *(const float4*)(Bs + kk * 128 + tx * 8);
      const float4 b1 = *(const float4*)(Bs + kk * 128 + tx * 8 + 4);
      const float av[8] = {a0.x, a0.y, a0.z, a0.w, a1.x, a1.y, a1.z, a1.w};
      const float bv[8] = {b0.x, b0.y, b0.z, b0.w, b1.x, b1.y, b1.z, b1.w};
      #pragma unroll
      for (int r = 0; r < 8; ++r)
        #pragma unroll
        for (int s = 0; s < 8; ++s)
          acc[r][s] = fmaf(av[r], bv[s], acc[r][s]);
    }
  }
  #pragma unroll
  for (int r = 0; r < 8; ++r) {
    size_t row = (size_t)(u0 + ty * 8 + r) * 4096 + v0 + tx * 8;
    float4 lo = {acc[r][0], acc[r][1], acc[r][2], acc[r][3]};
    float4 hi = {acc[r][4], acc[r][5], acc[r][6], acc[r][7]};
    *(float4*)(P + row) = lo;
    *(float4*)(P + row + 4) = hi;
  }
}

// ---------------- 9-tap diagonal sum + per-row partial argmax --------
__global__ __launch_bounds__(256)
void k_corr(const float* __restrict__ P, float* __restrict__ pv,
            int* __restrict__ pi) {
  __shared__ float lds[3 * 64 * 65];
  __shared__ float rv[256];
  __shared__ int   ri[256];
  const int t = threadIdx.x;
  const int qy = blockIdx.x, py = blockIdx.y;
  #pragma unroll
  for (int i = 0; i < 12; ++i) {
    int e = t + i * 256;
    int blk = e >> 10, rem = e & 1023;
    int ux = rem >> 4, v4 = (rem & 15) << 2;
    const float4 src = *(const float4*)(
        P + ((size_t)((py + blk) * 64 + ux)) * 4096 + (qy + blk) * 64 + v4);
    float* d = lds + blk * 4160 + ux * 65 + v4;
    d[0] = src.x; d[1] = src.y; d[2] = src.z; d[3] = src.w;
  }
  __syncthreads();
  const int px = t & 63, qg = t >> 6;
  float bv = -3.4e38f; int bq = 0;
  if (px < 62) {
    const int q0 = qg * 16;
    const int nq = (qg < 3) ? 16 : 14;
    const float* base = lds + px * 65 + q0;
    for (int l = 0; l < nq; ++l) {
      float s = 0.f;
      #pragma unroll
      for (int di = 0; di < 3; ++di)
        #pragma unroll
        for (int dj = 0; dj < 3; ++dj)
          s += base[di * 4160 + dj * 66 + l];
      if (s > bv) { bv = s; bq = q0 + l; }
    }
  }
  rv[t] = bv; ri[t] = bq;
  __syncthreads();
  if (t < 62) {
    float v = rv[t]; int q = ri[t];
    #pragma unroll
    for (int g = 1; g < 4; ++g) {
      float v2 = rv[g * 64 + t];
      if (v2 > v) { v = v2; q = ri[g * 64 + t]; }
    }
    const int n = py * 62 + t;
    pv[(size_t)n * 62 + qy] = v;
    pi[(size_t)n * 62 + qy] = qy * 62 + q;
  }
}

// ---------------- final argmax over the 62 qy partials ---------------
__global__ void k_argmax(const float* __restrict__ pv, const int* __restrict__ pi,
                         int* __restrict__ idxf) {
  int tid = blockIdx.x * 256 + threadIdx.x;
  if (tid >= 4 * 3844) return;
  const float* v = pv + (size_t)tid * 62;
  const int*  ii = pi + (size_t)tid * 62;
  float bv = v[0]; int bi = ii[0];
  for (int q = 1; q < 62; ++q) {
    float x = v[q];
    if (x > bv) { bv = x; bi = ii[q]; }
  }
  idxf[tid] = bi;
}

// ---------------- flow pyramid + 9 shifts ----------------------------
__global__ void k_flow(const int* __restrict__ idxf, float* __restrict__ out,
                       int Ho, int lg) {
  int gid = blockIdx.x * 256 + threadIdx.x;
  const int total = 4 * 9 * Ho * Ho;
  if (gid >= total) return;
  const int x = gid % Ho;
  const int y = (gid / Ho) % Ho;
  const int s = (gid / (Ho * Ho)) % 9;
  const int b = gid / (Ho * Ho * 9);
  const int i = s / 3, j = s % 3;
  const int sc = 1 << lg;
  const int yy = y - i * sc, xx = x - j * sc;
  float fw = 0.f, fh = 0.f;
  if (yy >= 0 && xx >= 0) {
    const int r = yy >> lg, c = xx >> lg;
    if (r < 62 && c < 62) {
      const int id = idxf[b * 3844 + r * 62 + c];
      fw = (float)((id % 62 - c) * sc);
      fh = (float)((id / 62 - r) * sc);
    }
  }
  float2 o = {fw, fh};
  *(float2*)(out + (size_t)gid * 2) = o;
}

// ---------------- weight prep: f32 OIHW -> bf16 hi/lo [oc][tap][cc][2][32]
__global__ void k_wprep(const float* __restrict__ w, ushort* __restrict__ wB,
                        int Cout, int CIN) {
  int gid = blockIdx.x * 256 + threadIdx.x;
  int total = Cout * 9 * CIN;
  if (gid >= total) return;
  const int NC = CIN >> 5;
  int wi = gid & 31;
  int r = gid >> 5;
  int cc = r % NC; r /= NC;
  int tap = r % 9;
  int oc = r / 9;
  int ci = cc * 32 + wi;
  float x = w[((size_t)oc * CIN + ci) * 9 + tap];
  ushort h = f2bf(x);
  ushort l = f2bf(x - bfval(h));
  size_t base = (((size_t)(oc * 9 + tap) * NC + cc) << 6) + wi;
  wB[base] = h;
  wB[base + 32] = l;
}

// ---------------- conv1_1: 3->64, fused input norm; f32 NCHW + bf16 hi/lo NHWC
__global__ __launch_bounds__(256)
void k_conv11(const float* __restrict__ img, const float* __restrict__ w,
              const float* __restrict__ bias, float* __restrict__ outF,
              ushort* __restrict__ outB) {
  __shared__ float wl[1728];
  __shared__ float bl[64];
  const int t = threadIdx.x;
  for (int i = t; i < 1728; i += 256) wl[i] = w[i];
  if (t < 64) bl[t] = bias[t];
  __syncthreads();
  const int x = t, y = blockIdx.x;
  const float mean[3] = {0.485f, 0.456f, 0.406f};
  const float stdv[3] = {0.229f, 0.224f, 0.225f};
  float v[27];
  #pragma unroll
  for (int c = 0; c < 3; ++c)
    #pragma unroll
    for (int dy = 0; dy < 3; ++dy)
      #pragma unroll
      for (int dx = 0; dx < 3; ++dx) {
        int iy = y + dy - 1, ix = x + dx - 1;
        float val = 0.f;
        if (iy >= 0 && iy < 256 && ix >= 0 && ix < 256)
          val = (img[((size_t)c * 256 + iy) * 256 + ix] - mean[c]) / stdv[c];
        v[c * 9 + dy * 3 + dx] = val;
      }
  float ov[64];
  #pragma unroll 4
  for (int oc = 0; oc < 64; ++oc) {
    float a = bl[oc];
    #pragma unroll
    for (int k = 0; k < 27; ++k) a = fmaf(wl[oc * 27 + k], v[k], a);
    a = fmaxf(a, 0.f);
    ov[oc] = a;
    outF[((size_t)oc * 256 + y) * 256 + x] = a;
  }
  // NHWC hi/lo: per pos 128 ushorts = [cc:2][hi32|lo32]
  uint* ob = (uint*)(outB + ((((size_t)y) * 256 + x) << 7));
  #pragma unroll
  for (int cc = 0; cc < 2; ++cc)
    #pragma unroll
    for (int i = 0; i < 16; ++i) {
      float v0 = ov[cc * 32 + 2 * i], v1 = ov[cc * 32 + 2 * i + 1];
      ushort h0 = f2bf(v0), h1 = f2bf(v1);
      ushort l0 = f2bf(v0 - bfval(h0)), l1 = f2bf(v1 - bfval(h1));
      ob[cc * 32 + i] = (uint)h0 | ((uint)h1 << 16);
      ob[cc * 32 + 16 + i] = (uint)l0 | ((uint)l1 << 16);
    }
}

// ---------------- MFMA 3x3 conv, bf16x3 (hi/lo) implicit GEMM --------
// in: NHWC hi/lo [H][W][CIN/32][2][32] bf16. wB: [oc][tap][CIN/32][2][32].
// block: 128 spatial (2 rows x 64) x 64 oc, 4 waves. Per-batch launch (z=1).
template <int CIN, bool POOL, bool WB16>
__global__ __launch_bounds__(256)
void k_mconv(const ushort* __restrict__ inb, const ushort* __restrict__ wB,
             const float* __restrict__ bias, float* __restrict__ outF,
             ushort* __restrict__ outB, int H, int W, int Cout) {
  __shared__ __align__(16) char lds_raw[33792];
  ushort* As = (ushort*)lds_raw;           // [264 pos][64] swizzled
  float*  sm = (float*)lds_raw;            // epilogue [128][65]
  const int t = threadIdx.x;
  const int xtiles = W >> 6;
  const int xt = blockIdx.x % xtiles;
  const int yp = blockIdx.x / xtiles;
  const int x0 = xt << 6, y0 = yp << 1;
  const int ocb = blockIdx.y << 6;
  const int lane = t & 63, wv = t >> 6;
  const int wm = wv >> 1, wn = wv & 1;
  const int lr = lane & 15, lk = lane >> 4;
  constexpr int NC = CIN / 32;

  f32x4 acc[4][2];
  #pragma unroll
  for (int mr = 0; mr < 4; ++mr)
    #pragma unroll
    for (int n = 0; n < 2; ++n) {
      f32x4 z = {0.f, 0.f, 0.f, 0.f};
      acc[mr][n] = z;
    }

  #pragma unroll 1
  for (int cc = 0; cc < NC; ++cc) {
    __syncthreads();
    // stage halo 4 x 66 positions x 64 (hi32|lo32 of chunk cc)
    #pragma unroll
    for (int i = 0; i < 9; ++i) {
      int e = t + i * 256;
      if (e < 2112) {
        int pos = e >> 3, cig = e & 7;
        int hy = pos / 66, hx = pos - hy * 66;
        int gy = y0 + hy - 1, gx = x0 + hx - 1;
        s16x8 v = {0, 0, 0, 0, 0, 0, 0, 0};
        if (gy >= 0 && gy < H && gx >= 0 && gx < W)
          v = *(const s16x8*)(inb + ((size_t)gy * W + gx) * (CIN * 2) +
                              cc * 64 + cig * 8);
        *(s16x8*)(As + ((pos << 3) + (cig ^ (pos & 7))) * 8) = v;
      }
    }
    __syncthreads();
    #pragma unroll 3
    for (int tap = 0; tap < 9; ++tap) {
      const int dy = tap / 3, dx = tap % 3;
      s16x8 bh[2], blo[2];
      #pragma unroll
      for (int n = 0; n < 2; ++n) {
        const ushort* wp =
            wB + (((size_t)(ocb + wn * 32 + n * 16 + lr) * 9 + tap) * NC + cc) * 64 +
            lk * 8;
        bh[n]  = *(const s16x8*)wp;
        blo[n] = *(const s16x8*)(wp + 32);
      }
      #pragma unroll
      for (int mr = 0; mr < 4; ++mr) {
        const int pos = (wm + dy) * 66 + mr * 16 + lr + dx;
        s16x8 ah = *(const s16x8*)(As + ((pos << 3) + (lk ^ (pos & 7))) * 8);
        s16x8 al = *(const s16x8*)(As + ((pos << 3) + ((4 + lk) ^ (pos & 7))) * 8);
        #pragma unroll
        for (int n = 0; n < 2; ++n) {
          acc[mr][n] = __builtin_amdgcn_mfma_f32_16x16x32_bf16(al, bh[n], acc[mr][n], 0, 0, 0);
          acc[mr][n] = __builtin_amdgcn_mfma_f32_16x16x32_bf16(ah, blo[n], acc[mr][n], 0, 0, 0);
          acc[mr][n] = __builtin_amdgcn_mfma_f32_16x16x32_bf16(ah, bh[n], acc[mr][n], 0, 0, 0);
        }
      }
    }
  }
  __syncthreads();
  // bias + relu into sm[sp][oc], stride 65 (D: col=lane&15, row=(lane>>4)*4+r)
  #pragma unroll
  for (int mr = 0; mr < 4; ++mr)
    #pragma unroll
    for (int n = 0; n < 2; ++n) {
      const int oc = wn * 32 + n * 16 + lr;
      const float bs = bias[ocb + oc];
      #pragma unroll
      for (int r = 0; r < 4; ++r)
        sm[(wm * 64 + mr * 16 + lk * 4 + r) * 65 + oc] =
            fmaxf(acc[mr][n][r] + bs, 0.f);
    }
  __syncthreads();
  if (POOL) {
    const int Wo = W >> 1;
    #pragma unroll
    for (int i = 0; i < 4; ++i) {
      int e = t + i * 256;               // 1024 = 32 xo * 32 oc-pairs
      int op = e & 31, xo = e >> 5;
      int oc0 = op * 2;
      float m0 = fmaxf(fmaxf(sm[(xo * 2) * 65 + oc0], sm[(xo * 2 + 1) * 65 + oc0]),
                       fmaxf(sm[(64 + xo * 2) * 65 + oc0], sm[(64 + xo * 2 + 1) * 65 + oc0]));
      float m1 = fmaxf(fmaxf(sm[(xo * 2) * 65 + oc0 + 1], sm[(xo * 2 + 1) * 65 + oc0 + 1]),
                       fmaxf(sm[(64 + xo * 2) * 65 + oc0 + 1], sm[(64 + xo * 2 + 1) * 65 + oc0 + 1]));
      ushort h0 = f2bf(m0), h1 = f2bf(m1);
      ushort l0 = f2bf(m0 - bfval(h0)), l1 = f2bf(m1 - bfval(h1));
      int cg = ocb + oc0;
      size_t pos = (size_t)yp * Wo + (x0 >> 1) + xo;
      size_t base = pos * (size_t)(2 * Cout) + ((size_t)(cg >> 5) << 6) + (cg & 31);
      uint* ob = (uint*)outB;
      ob[base >> 1] = (uint)h0 | ((uint)h1 << 16);
      ob[(base + 32) >> 1] = (uint)l0 | ((uint)l1 << 16);
    }
  } else {
    #pragma unroll
    for (int i = 0; i < 32; ++i) {
      int e = t + i * 256;
      int oc = e >> 7, sp = e & 127;
      outF[((size_t)(ocb + oc) * H + y0 + (sp >> 6)) * W + x0 + (sp & 63)] =
          sm[sp * 65 + oc];
    }
    if (WB16) {
      #pragma unroll
      for (int i = 0; i < 16; ++i) {
        int e = t + i * 256;             // 4096 = 128 sp * 32 oc-pairs
        int op = e & 31, sp = e >> 5;
        int oc0 = op * 2;
        float v0 = sm[sp * 65 + oc0], v1 = sm[sp * 65 + oc0 + 1];
        ushort h0 = f2bf(v0), h1 = f2bf(v1);
        ushort l0 = f2bf(v0 - bfval(h0)), l1 = f2bf(v1 - bfval(h1));
        int cg = ocb + oc0;
        size_t pos = ((size_t)(y0 + (sp >> 6))) * W + x0 + (sp & 63);
        size_t base = pos * (size_t)(2 * Cout) + ((size_t)(cg >> 5) << 6) + (cg & 31);
        uint* ob = (uint*)outB;
        ob[base >> 1] = (uint)h0 | ((uint)h1 << 16);
        ob[(base + 32) >> 1] = (uint)l0 | ((uint)l1 << 16);
      }
    }
  }
}

// ---------------------------------------------------------------------
extern "C" void kernel_launch(void* const* d_in, const int* in_sizes, int n_in,
                              void* d_out, int out_size, void* d_ws, size_t ws_size,
                              hipStream_t stream) {
  const float* df1 = (const float*)d_in[0];
  const float* df2 = (const float*)d_in[1];
  const float* img = (const float*)d_in[2];
  const float* w11 = (const float*)d_in[3];
  const float* b11 = (const float*)d_in[4];
  const float* w12 = (const float*)d_in[5];
  const float* b12 = (const float*)d_in[6];
  const float* w21 = (const float*)d_in[7];
  const float* b21 = (const float*)d_in[8];
  const float* w22 = (const float*)d_in[9];
  const float* b22 = (const float*)d_in[10];
  const float* w31 = (const float*)d_in[11];
  const float* b31 = (const float*)d_in[12];
  float* out = (float*)d_out;

  // ---- ws scratch (~2.27 MB): argmax indices + bf16 hi/lo weights
  int* idxf = (int*)d_ws;
  ushort* w12b = (ushort*)(idxf + 15376);     //  64*9*2*64  = 73728
  ushort* w21b = w12b + 73728;                // 128*9*2*64  = 147456
  ushort* w22b = w21b + 147456;               // 128*9*4*64  = 294912
  ushort* w31b = w22b + 294912;               // 256*9*4*64  = 589824

  // ---- correspondence scratch overlays (dead before real outputs land)
  float* n1 = out + R21_OFF;                  // normalized fin (4 x 1M)
  float* n2 = n1 + 4194304;
  float* P  = out + R11_OFF;                  // 4096^2
  float* pv = out + OFF1_OFF;
  int*   pi = (int*)(out + OFF1_OFF + 953312);

  k_normalize<<<dim3(64, 4, 2), 256, 0, stream>>>(df1, df2, n1, n2);
  k_wprep<<<(64 * 9 * 64 + 255) / 256, 256, 0, stream>>>(w12, w12b, 64, 64);
  k_wprep<<<(128 * 9 * 64 + 255) / 256, 256, 0, stream>>>(w21, w21b, 128, 64);
  k_wprep<<<(128 * 9 * 128 + 255) / 256, 256, 0, stream>>>(w22, w22b, 128, 128);
  k_wprep<<<(256 * 9 * 128 + 255) / 256, 256, 0, stream>>>(w31, w31b, 256, 128);

  for (int b = 0; b < 4; ++b) {
    k_pgemm<<<dim3(32, 32), 256, 0, stream>>>(n1 + (size_t)b * 1048576,
                                              n2 + (size_t)b * 1048576, P);
    k_corr<<<dim3(62, 62), 256, 0, stream>>>(P, pv + (size_t)b * 238328,
                                             pi + (size_t)b * 238328);
  }
  k_argmax<<<(15376 + 255) / 256, 256, 0, stream>>>(pv, pi, idxf);

  // ---- VGG chain, per batch; bf16 hi/lo activations live in the
  // off1/off2/off3 pool (24.8 MB, rewritten by k_flow at the very end)
  ushort* S = (ushort*)out;
  ushort* a11s = S;                 // [0 .. 8,388,608)   16.8 MB
  ushort* p1bs = S + 8388608;       // [8.39M .. 10.49M)   4.2 MB
  ushort* a21s = S;                 // reuse [0 .. 4,194,304)
  ushort* p2bs = S + 4194304;       // [4.19M .. 5.24M)

  for (int b = 0; b < 4; ++b) {
    k_conv11<<<dim3(256, 1), 256, 0, stream>>>(
        img + (size_t)b * 3 * 65536, w11, b11,
        out + R11_OFF + (size_t)b * 64 * 65536, a11s);
    k_mconv<64, true, false><<<dim3(512, 1, 1), 256, 0, stream>>>(
        a11s, w12b, b12, nullptr, p1bs, 256, 256, 64);
    k_mconv<64, false, true><<<dim3(128, 2, 1), 256, 0, stream>>>(
        p1bs, w21b, b21, out + R21_OFF + (size_t)b * 128 * 16384, a21s, 128, 128, 128);
    k_mconv<128, true, false><<<dim3(128, 2, 1), 256, 0, stream>>>(
        a21s, w22b, b22, nullptr, p2bs, 128, 128, 128);
    k_mconv<128, false, false><<<dim3(32, 4, 1), 256, 0, stream>>>(
        p2bs, w31b, b31, out + R31_OFF + (size_t)b * 256 * 4096, nullptr, 64, 64, 256);
  }

  // ---- offset pyramids last (overwrite the VGG bf16 scratch pool)
  k_flow<<<(4 * 9 * 256 * 256 + 255) / 256, 256, 0, stream>>>(idxf, out + OFF1_OFF, 256, 2);
  k_flow<<<(4 * 9 * 128 * 128 + 255) / 256, 256, 0, stream>>>(idxf, out + OFF2_OFF, 128, 1);
  k_flow<<<(4 * 9 * 64 * 64 + 255) / 256, 256, 0, stream>>>(idxf, out + OFF3_OFF, 64, 0);
}

// Round 3
// 913.365 us; speedup vs baseline: 2.3064x; 1.3400x over previous
//
#include <hip/hip_runtime.h>

typedef __attribute__((ext_vector_type(4))) float f32x4;
typedef __attribute__((ext_vector_type(8))) short s16x8;

// ---------------- output layout (float element offsets) ----------------
#define OFF1_OFF 0
#define OFF2_OFF 4718592
#define OFF3_OFF 5898240
#define R11_OFF  6193152      // 4*64*256*256 = 16,777,216 = 4096^2 (P scratch)
#define R21_OFF  22970368     // 4*128*128*128 = 8,388,608 (n1b+n2b scratch)
#define R31_OFF  31358976     // 4*256*64*64 = 4,194,304

__device__ __forceinline__ ushort f2bf(float x) {
  union { float f; uint u; } c; c.f = x;
  uint r = c.u + 0x7FFFu + ((c.u >> 16) & 1u);
  return (ushort)(r >> 16);
}
__device__ __forceinline__ float bfval(ushort h) {
  union { uint u; float f; } c; c.u = ((uint)h) << 16;
  return c.f;
}

// ---------------- per-pixel channel L2 normalize -> bf16 hi/lo pos-major
// out layout per sample: [pos 4096][cc 8][hi 32 | lo 32] ushort (512/pos).
// grid (64 h, 4 b, 2 tensor), block 256 (4 cgroups x 64 x).
__global__ __launch_bounds__(256)
void k_normalize(const float* __restrict__ f1, const float* __restrict__ f2,
                 ushort* __restrict__ n1b, ushort* __restrict__ n2b) {
  __shared__ uint ldsu[64 * 256];            // 64 KB; red/inv aliased below
  float* red = (float*)ldsu;                 // [256]
  float* inv = (float*)ldsu + 256;           // [64]
  const int t = threadIdx.x, x = t & 63, cg = t >> 6;
  const int h = blockIdx.x, b = blockIdx.y;
  const float* in = blockIdx.z ? f2 : f1;
  ushort* op = blockIdx.z ? n2b : n1b;
  const size_t base = (size_t)b * 256 * 4096 + (size_t)h * 64 + x;
  float vals[64];
  float s = 0.f;
  #pragma unroll
  for (int ci = 0; ci < 64; ++ci) {
    float v = in[base + (size_t)(cg * 64 + ci) * 4096];
    vals[ci] = v;
    s = fmaf(v, v, s);
  }
  red[t] = s;
  __syncthreads();
  if (t < 64) {
    float tot = red[t] + red[64 + t] + red[128 + t] + red[192 + t];
    inv[t] = 1.0f / fmaxf(sqrtf(tot), 1e-12f);
  }
  __syncthreads();
  const float iv = inv[x];
  __syncthreads();                           // all reads of inv done before clobber
  #pragma unroll
  for (int j = 0; j < 32; ++j) {
    float v0 = vals[2 * j] * iv, v1 = vals[2 * j + 1] * iv;
    ushort h0 = f2bf(v0), h1 = f2bf(v1);
    ushort l0 = f2bf(v0 - bfval(h0)), l1 = f2bf(v1 - bfval(h1));
    int cc = (cg << 1) + (j >> 4);
    int i = j & 15;
    int qh = cc * 32 + i, ql = cc * 32 + 16 + i;
    ldsu[x * 256 + (qh ^ (x & 31))] = (uint)h0 | ((uint)h1 << 16);
    ldsu[x * 256 + (ql ^ (x & 31))] = (uint)l0 | ((uint)l1 << 16);
  }
  __syncthreads();
  uint* og = (uint*)(op + ((size_t)b * 4096 + h * 64) * 512);
  #pragma unroll
  for (int it = 0; it < 64; ++it) {
    int idx = it * 256 + t;
    int p = idx >> 8, q = idx & 255;
    og[idx] = ldsu[p * 256 + (q ^ (p & 31))];
  }
}

// ---------------- pixel-correlation GEMM (MFMA bf16x3): P = A^T B -----
// Ab/Bb: [4096 pos][cc 8][hi32|lo32]. P: [4096][4096] f32. 128x128 tile.
__global__ __launch_bounds__(256)
void k_pgemm_mfma(const ushort* __restrict__ Ab, const ushort* __restrict__ Bb,
                  float* __restrict__ P) {
  __shared__ __align__(16) ushort As[128 * 64];
  __shared__ __align__(16) ushort Bs[128 * 64];
  const int t = threadIdx.x;
  const int u0 = blockIdx.y * 128, v0 = blockIdx.x * 128;
  const int lane = t & 63, wv = t >> 6;
  const int wm = wv >> 1, wn = wv & 1;
  const int lr = lane & 15, lk = lane >> 4;
  f32x4 acc[4][4];
  #pragma unroll
  for (int mt = 0; mt < 4; ++mt)
    #pragma unroll
    for (int nt = 0; nt < 4; ++nt) {
      f32x4 z = {0.f, 0.f, 0.f, 0.f};
      acc[mt][nt] = z;
    }

  #pragma unroll 1
  for (int cc = 0; cc < 8; ++cc) {
    __syncthreads();
    #pragma unroll
    for (int i = 0; i < 4; ++i) {
      int e = t + i * 256;                  // 1024 slot-loads per tile
      int row = e >> 3, slot = e & 7;
      s16x8 va = *(const s16x8*)(Ab + ((size_t)(u0 + row)) * 512 + cc * 64 + slot * 8);
      *(s16x8*)(As + ((row << 3) + (slot ^ (row & 7))) * 8) = va;
      s16x8 vb = *(const s16x8*)(Bb + ((size_t)(v0 + row)) * 512 + cc * 64 + slot * 8);
      *(s16x8*)(Bs + ((row << 3) + (slot ^ (row & 7))) * 8) = vb;
    }
    __syncthreads();
    s16x8 ah[4], al[4], bh[4], bl[4];
    #pragma unroll
    for (int mt = 0; mt < 4; ++mt) {
      int row = wm * 64 + mt * 16 + lr;
      ah[mt] = *(const s16x8*)(As + ((row << 3) + (lk ^ (row & 7))) * 8);
      al[mt] = *(const s16x8*)(As + ((row << 3) + ((4 + lk) ^ (row & 7))) * 8);
    }
    #pragma unroll
    for (int nt = 0; nt < 4; ++nt) {
      int row = wn * 64 + nt * 16 + lr;
      bh[nt] = *(const s16x8*)(Bs + ((row << 3) + (lk ^ (row & 7))) * 8);
      bl[nt] = *(const s16x8*)(Bs + ((row << 3) + ((4 + lk) ^ (row & 7))) * 8);
    }
    #pragma unroll
    for (int mt = 0; mt < 4; ++mt)
      #pragma unroll
      for (int nt = 0; nt < 4; ++nt) {
        acc[mt][nt] = __builtin_amdgcn_mfma_f32_16x16x32_bf16(al[mt], bh[nt], acc[mt][nt], 0, 0, 0);
        acc[mt][nt] = __builtin_amdgcn_mfma_f32_16x16x32_bf16(ah[mt], bl[nt], acc[mt][nt], 0, 0, 0);
        acc[mt][nt] = __builtin_amdgcn_mfma_f32_16x16x32_bf16(ah[mt], bh[nt], acc[mt][nt], 0, 0, 0);
      }
  }
  // D layout: col = lane&15 (v), row = (lane>>4)*4 + r (u)
  #pragma unroll
  for (int mt = 0; mt < 4; ++mt)
    #pragma unroll
    for (int nt = 0; nt < 4; ++nt) {
      #pragma unroll
      for (int r = 0; r < 4; ++r)
        P[(size_t)(u0 + wm * 64 + mt * 16 + lk * 4 + r) * 4096 +
          v0 + wn * 64 + nt * 16 + lr] = acc[mt][nt][r];
    }
}

// ---------------- 9-tap diagonal sum + per-row partial argmax --------
__global__ __launch_bounds__(256)
void k_corr(const float* __restrict__ P, float* __restrict__ pv,
            int* __restrict__ pi) {
  __shared__ float lds[3 * 64 * 65];
  __shared__ float rv[256];
  __shared__ int   ri[256];
  const int t = threadIdx.x;
  const int qy = blockIdx.x, py = blockIdx.y;
  #pragma unroll
  for (int i = 0; i < 12; ++i) {
    int e = t + i * 256;
    int blk = e >> 10, rem = e & 1023;
    int ux = rem >> 4, v4 = (rem & 15) << 2;
    const float4 src = *(const float4*)(
        P + ((size_t)((py + blk) * 64 + ux)) * 4096 + (qy + blk) * 64 + v4);
    float* d = lds + blk * 4160 + ux * 65 + v4;
    d[0] = src.x; d[1] = src.y; d[2] = src.z; d[3] = src.w;
  }
  __syncthreads();
  const int px = t & 63, qg = t >> 6;
  float bv = -3.4e38f; int bq = 0;
  if (px < 62) {
    const int q0 = qg * 16;
    const int nq = (qg < 3) ? 16 : 14;
    const float* base = lds + px * 65 + q0;
    for (int l = 0; l < nq; ++l) {
      float s = 0.f;
      #pragma unroll
      for (int di = 0; di < 3; ++di)
        #pragma unroll
        for (int dj = 0; dj < 3; ++dj)
          s += base[di * 4160 + dj * 66 + l];
      if (s > bv) { bv = s; bq = q0 + l; }
    }
  }
  rv[t] = bv; ri[t] = bq;
  __syncthreads();
  if (t < 62) {
    float v = rv[t]; int q = ri[t];
    #pragma unroll
    for (int g = 1; g < 4; ++g) {
      float v2 = rv[g * 64 + t];
      if (v2 > v) { v = v2; q = ri[g * 64 + t]; }
    }
    const int n = py * 62 + t;
    pv[(size_t)n * 62 + qy] = v;
    pi[(size_t)n * 62 + qy] = qy * 62 + q;
  }
}

// ---------------- final argmax over the 62 qy partials ---------------
__global__ void k_argmax(const float* __restrict__ pv, const int* __restrict__ pi,
                         int* __restrict__ idxf) {
  int tid = blockIdx.x * 256 + threadIdx.x;
  if (tid >= 4 * 3844) return;
  const float* v = pv + (size_t)tid * 62;
  const int*  ii = pi + (size_t)tid * 62;
  float bv = v[0]; int bi = ii[0];
  for (int q = 1; q < 62; ++q) {
    float x = v[q];
    if (x > bv) { bv = x; bi = ii[q]; }
  }
  idxf[tid] = bi;
}

// ---------------- flow pyramid + 9 shifts ----------------------------
__global__ void k_flow(const int* __restrict__ idxf, float* __restrict__ out,
                       int Ho, int lg) {
  int gid = blockIdx.x * 256 + threadIdx.x;
  const int total = 4 * 9 * Ho * Ho;
  if (gid >= total) return;
  const int x = gid % Ho;
  const int y = (gid / Ho) % Ho;
  const int s = (gid / (Ho * Ho)) % 9;
  const int b = gid / (Ho * Ho * 9);
  const int i = s / 3, j = s % 3;
  const int sc = 1 << lg;
  const int yy = y - i * sc, xx = x - j * sc;
  float fw = 0.f, fh = 0.f;
  if (yy >= 0 && xx >= 0) {
    const int r = yy >> lg, c = xx >> lg;
    if (r < 62 && c < 62) {
      const int id = idxf[b * 3844 + r * 62 + c];
      fw = (float)((id % 62 - c) * sc);
      fh = (float)((id / 62 - r) * sc);
    }
  }
  float2 o = {fw, fh};
  *(float2*)(out + (size_t)gid * 2) = o;
}

// ---------------- weight prep: f32 OIHW -> bf16 hi/lo [oc][tap][cc][2][32]
__global__ void k_wprep(const float* __restrict__ w, ushort* __restrict__ wB,
                        int Cout, int CIN) {
  int gid = blockIdx.x * 256 + threadIdx.x;
  int total = Cout * 9 * CIN;
  if (gid >= total) return;
  const int NC = CIN >> 5;
  int wi = gid & 31;
  int r = gid >> 5;
  int cc = r % NC; r /= NC;
  int tap = r % 9;
  int oc = r / 9;
  int ci = cc * 32 + wi;
  float x = w[((size_t)oc * CIN + ci) * 9 + tap];
  ushort h = f2bf(x);
  ushort l = f2bf(x - bfval(h));
  size_t base = (((size_t)(oc * 9 + tap) * NC + cc) << 6) + wi;
  wB[base] = h;
  wB[base + 32] = l;
}

// ---------------- conv1_1: 3->64, fused input norm; f32 NCHW + bf16 hi/lo NHWC
__global__ __launch_bounds__(256)
void k_conv11(const float* __restrict__ img, const float* __restrict__ w,
              const float* __restrict__ bias, float* __restrict__ outF,
              ushort* __restrict__ outB) {
  __shared__ float wl[1728];
  __shared__ float bl[64];
  const int t = threadIdx.x;
  for (int i = t; i < 1728; i += 256) wl[i] = w[i];
  if (t < 64) bl[t] = bias[t];
  __syncthreads();
  const int x = t, y = blockIdx.x;
  const float mean[3] = {0.485f, 0.456f, 0.406f};
  const float stdv[3] = {0.229f, 0.224f, 0.225f};
  float v[27];
  #pragma unroll
  for (int c = 0; c < 3; ++c)
    #pragma unroll
    for (int dy = 0; dy < 3; ++dy)
      #pragma unroll
      for (int dx = 0; dx < 3; ++dx) {
        int iy = y + dy - 1, ix = x + dx - 1;
        float val = 0.f;
        if (iy >= 0 && iy < 256 && ix >= 0 && ix < 256)
          val = (img[((size_t)c * 256 + iy) * 256 + ix] - mean[c]) / stdv[c];
        v[c * 9 + dy * 3 + dx] = val;
      }
  float ov[64];
  #pragma unroll 4
  for (int oc = 0; oc < 64; ++oc) {
    float a = bl[oc];
    #pragma unroll
    for (int k = 0; k < 27; ++k) a = fmaf(wl[oc * 27 + k], v[k], a);
    a = fmaxf(a, 0.f);
    ov[oc] = a;
    outF[((size_t)oc * 256 + y) * 256 + x] = a;
  }
  uint* ob = (uint*)(outB + ((((size_t)y) * 256 + x) << 7));
  #pragma unroll
  for (int cc = 0; cc < 2; ++cc)
    #pragma unroll
    for (int i = 0; i < 16; ++i) {
      float v0 = ov[cc * 32 + 2 * i], v1 = ov[cc * 32 + 2 * i + 1];
      ushort h0 = f2bf(v0), h1 = f2bf(v1);
      ushort l0 = f2bf(v0 - bfval(h0)), l1 = f2bf(v1 - bfval(h1));
      ob[cc * 32 + i] = (uint)h0 | ((uint)h1 << 16);
      ob[cc * 32 + 16 + i] = (uint)l0 | ((uint)l1 << 16);
    }
}

// ---------------- MFMA 3x3 conv, bf16x3 (hi/lo) implicit GEMM --------
template <int CIN, bool POOL, bool WB16>
__global__ __launch_bounds__(256)
void k_mconv(const ushort* __restrict__ inb, const ushort* __restrict__ wB,
             const float* __restrict__ bias, float* __restrict__ outF,
             ushort* __restrict__ outB, int H, int W, int Cout) {
  __shared__ __align__(16) char lds_raw[33792];
  ushort* As = (ushort*)lds_raw;           // [264 pos][64] swizzled
  float*  sm = (float*)lds_raw;            // epilogue [128][65]
  const int t = threadIdx.x;
  const int xtiles = W >> 6;
  const int xt = blockIdx.x % xtiles;
  const int yp = blockIdx.x / xtiles;
  const int x0 = xt << 6, y0 = yp << 1;
  const int ocb = blockIdx.y << 6;
  const int lane = t & 63, wv = t >> 6;
  const int wm = wv >> 1, wn = wv & 1;
  const int lr = lane & 15, lk = lane >> 4;
  constexpr int NC = CIN / 32;

  f32x4 acc[4][2];
  #pragma unroll
  for (int mr = 0; mr < 4; ++mr)
    #pragma unroll
    for (int n = 0; n < 2; ++n) {
      f32x4 z = {0.f, 0.f, 0.f, 0.f};
      acc[mr][n] = z;
    }

  #pragma unroll 1
  for (int cc = 0; cc < NC; ++cc) {
    __syncthreads();
    #pragma unroll
    for (int i = 0; i < 9; ++i) {
      int e = t + i * 256;
      if (e < 2112) {
        int pos = e >> 3, cig = e & 7;
        int hy = pos / 66, hx = pos - hy * 66;
        int gy = y0 + hy - 1, gx = x0 + hx - 1;
        s16x8 v = {0, 0, 0, 0, 0, 0, 0, 0};
        if (gy >= 0 && gy < H && gx >= 0 && gx < W)
          v = *(const s16x8*)(inb + ((size_t)gy * W + gx) * (CIN * 2) +
                              cc * 64 + cig * 8);
        *(s16x8*)(As + ((pos << 3) + (cig ^ (pos & 7))) * 8) = v;
      }
    }
    __syncthreads();
    #pragma unroll 3
    for (int tap = 0; tap < 9; ++tap) {
      const int dy = tap / 3, dx = tap % 3;
      s16x8 bh[2], blo[2];
      #pragma unroll
      for (int n = 0; n < 2; ++n) {
        const ushort* wp =
            wB + (((size_t)(ocb + wn * 32 + n * 16 + lr) * 9 + tap) * NC + cc) * 64 +
            lk * 8;
        bh[n]  = *(const s16x8*)wp;
        blo[n] = *(const s16x8*)(wp + 32);
      }
      #pragma unroll
      for (int mr = 0; mr < 4; ++mr) {
        const int pos = (wm + dy) * 66 + mr * 16 + lr + dx;
        s16x8 ah = *(const s16x8*)(As + ((pos << 3) + (lk ^ (pos & 7))) * 8);
        s16x8 al = *(const s16x8*)(As + ((pos << 3) + ((4 + lk) ^ (pos & 7))) * 8);
        #pragma unroll
        for (int n = 0; n < 2; ++n) {
          acc[mr][n] = __builtin_amdgcn_mfma_f32_16x16x32_bf16(al, bh[n], acc[mr][n], 0, 0, 0);
          acc[mr][n] = __builtin_amdgcn_mfma_f32_16x16x32_bf16(ah, blo[n], acc[mr][n], 0, 0, 0);
          acc[mr][n] = __builtin_amdgcn_mfma_f32_16x16x32_bf16(ah, bh[n], acc[mr][n], 0, 0, 0);
        }
      }
    }
  }
  __syncthreads();
  #pragma unroll
  for (int mr = 0; mr < 4; ++mr)
    #pragma unroll
    for (int n = 0; n < 2; ++n) {
      const int oc = wn * 32 + n * 16 + lr;
      const float bs = bias[ocb + oc];
      #pragma unroll
      for (int r = 0; r < 4; ++r)
        sm[(wm * 64 + mr * 16 + lk * 4 + r) * 65 + oc] =
            fmaxf(acc[mr][n][r] + bs, 0.f);
    }
  __syncthreads();
  if (POOL) {
    const int Wo = W >> 1;
    #pragma unroll
    for (int i = 0; i < 4; ++i) {
      int e = t + i * 256;
      int op = e & 31, xo = e >> 5;
      int oc0 = op * 2;
      float m0 = fmaxf(fmaxf(sm[(xo * 2) * 65 + oc0], sm[(xo * 2 + 1) * 65 + oc0]),
                       fmaxf(sm[(64 + xo * 2) * 65 + oc0], sm[(64 + xo * 2 + 1) * 65 + oc0]));
      float m1 = fmaxf(fmaxf(sm[(xo * 2) * 65 + oc0 + 1], sm[(xo * 2 + 1) * 65 + oc0 + 1]),
                       fmaxf(sm[(64 + xo * 2) * 65 + oc0 + 1], sm[(64 + xo * 2 + 1) * 65 + oc0 + 1]));
      ushort h0 = f2bf(m0), h1 = f2bf(m1);
      ushort l0 = f2bf(m0 - bfval(h0)), l1 = f2bf(m1 - bfval(h1));
      int cg = ocb + oc0;
      size_t pos = (size_t)yp * Wo + (x0 >> 1) + xo;
      size_t base = pos * (size_t)(2 * Cout) + ((size_t)(cg >> 5) << 6) + (cg & 31);
      uint* ob = (uint*)outB;
      ob[base >> 1] = (uint)h0 | ((uint)h1 << 16);
      ob[(base + 32) >> 1] = (uint)l0 | ((uint)l1 << 16);
    }
  } else {
    #pragma unroll
    for (int i = 0; i < 32; ++i) {
      int e = t + i * 256;
      int oc = e >> 7, sp = e & 127;
      outF[((size_t)(ocb + oc) * H + y0 + (sp >> 6)) * W + x0 + (sp & 63)] =
          sm[sp * 65 + oc];
    }
    if (WB16) {
      #pragma unroll
      for (int i = 0; i < 16; ++i) {
        int e = t + i * 256;
        int op = e & 31, sp = e >> 5;
        int oc0 = op * 2;
        float v0 = sm[sp * 65 + oc0], v1 = sm[sp * 65 + oc0 + 1];
        ushort h0 = f2bf(v0), h1 = f2bf(v1);
        ushort l0 = f2bf(v0 - bfval(h0)), l1 = f2bf(v1 - bfval(h1));
        int cg = ocb + oc0;
        size_t pos = ((size_t)(y0 + (sp >> 6))) * W + x0 + (sp & 63);
        size_t base = pos * (size_t)(2 * Cout) + ((size_t)(cg >> 5) << 6) + (cg & 31);
        uint* ob = (uint*)outB;
        ob[base >> 1] = (uint)h0 | ((uint)h1 << 16);
        ob[(base + 32) >> 1] = (uint)l0 | ((uint)l1 << 16);
      }
    }
  }
}

// ---------------------------------------------------------------------
extern "C" void kernel_launch(void* const* d_in, const int* in_sizes, int n_in,
                              void* d_out, int out_size, void* d_ws, size_t ws_size,
                              hipStream_t stream) {
  const float* df1 = (const float*)d_in[0];
  const float* df2 = (const float*)d_in[1];
  const float* img = (const float*)d_in[2];
  const float* w11 = (const float*)d_in[3];
  const float* b11 = (const float*)d_in[4];
  const float* w12 = (const float*)d_in[5];
  const float* b12 = (const float*)d_in[6];
  const float* w21 = (const float*)d_in[7];
  const float* b21 = (const float*)d_in[8];
  const float* w22 = (const float*)d_in[9];
  const float* b22 = (const float*)d_in[10];
  const float* w31 = (const float*)d_in[11];
  const float* b31 = (const float*)d_in[12];
  float* out = (float*)d_out;

  // ---- ws scratch (~2.27 MB): argmax indices + bf16 hi/lo weights
  int* idxf = (int*)d_ws;
  ushort* w12b = (ushort*)(idxf + 15376);
  ushort* w21b = w12b + 73728;
  ushort* w22b = w21b + 147456;
  ushort* w31b = w22b + 294912;

  // ---- correspondence scratch overlays (dead before real outputs land)
  // n1b/n2b: 2 x 4 samples x 4096 pos x 512 ushort = exactly R21 region.
  ushort* n1b = (ushort*)(out + R21_OFF);
  ushort* n2b = n1b + 8388608;
  float* P  = out + R11_OFF;                  // 4096^2
  float* pv = out + OFF1_OFF;
  int*   pi = (int*)(out + OFF1_OFF + 953312);

  k_normalize<<<dim3(64, 4, 2), 256, 0, stream>>>(df1, df2, n1b, n2b);
  k_wprep<<<(64 * 9 * 64 + 255) / 256, 256, 0, stream>>>(w12, w12b, 64, 64);
  k_wprep<<<(128 * 9 * 64 + 255) / 256, 256, 0, stream>>>(w21, w21b, 128, 64);
  k_wprep<<<(128 * 9 * 128 + 255) / 256, 256, 0, stream>>>(w22, w22b, 128, 128);
  k_wprep<<<(256 * 9 * 128 + 255) / 256, 256, 0, stream>>>(w31, w31b, 256, 128);

  for (int b = 0; b < 4; ++b) {
    k_pgemm_mfma<<<dim3(32, 32), 256, 0, stream>>>(n1b + (size_t)b * 2097152,
                                                   n2b + (size_t)b * 2097152, P);
    k_corr<<<dim3(62, 62), 256, 0, stream>>>(P, pv + (size_t)b * 238328,
                                             pi + (size_t)b * 238328);
  }
  k_argmax<<<(15376 + 255) / 256, 256, 0, stream>>>(pv, pi, idxf);

  // ---- VGG chain, per batch; bf16 hi/lo activations live in the
  // off1/off2/off3 pool (24.8 MB, rewritten by k_flow at the very end)
  ushort* S = (ushort*)out;
  ushort* a11s = S;                 // [0 .. 8,388,608)
  ushort* p1bs = S + 8388608;
  ushort* a21s = S;
  ushort* p2bs = S + 4194304;

  for (int b = 0; b < 4; ++b) {
    k_conv11<<<dim3(256, 1), 256, 0, stream>>>(
        img + (size_t)b * 3 * 65536, w11, b11,
        out + R11_OFF + (size_t)b * 64 * 65536, a11s);
    k_mconv<64, true, false><<<dim3(512, 1, 1), 256, 0, stream>>>(
        a11s, w12b, b12, nullptr, p1bs, 256, 256, 64);
    k_mconv<64, false, true><<<dim3(128, 2, 1), 256, 0, stream>>>(
        p1bs, w21b, b21, out + R21_OFF + (size_t)b * 128 * 16384, a21s, 128, 128, 128);
    k_mconv<128, true, false><<<dim3(128, 2, 1), 256, 0, stream>>>(
        a21s, w22b, b22, nullptr, p2bs, 128, 128, 128);
    k_mconv<128, false, false><<<dim3(32, 4, 1), 256, 0, stream>>>(
        p2bs, w31b, b31, out + R31_OFF + (size_t)b * 256 * 4096, nullptr, 64, 64, 256);
  }

  // ---- offset pyramids last (overwrite the VGG bf16 scratch pool)
  k_flow<<<(4 * 9 * 256 * 256 + 255) / 256, 256, 0, stream>>>(idxf, out + OFF1_OFF, 256, 2);
  k_flow<<<(4 * 9 * 128 * 128 + 255) / 256, 256, 0, stream>>>(idxf, out + OFF2_OFF, 128, 1);
  k_flow<<<(4 * 9 * 64 * 64 + 255) / 256, 256, 0, stream>>>(idxf, out + OFF3_OFF, 64, 0);
}

// Round 4
// 619.426 us; speedup vs baseline: 3.4008x; 1.4745x over previous
//
#include <hip/hip_runtime.h>

typedef __attribute__((ext_vector_type(4))) float f32x4;
typedef __attribute__((ext_vector_type(8))) short s16x8;

// ---------------- output layout (float element offsets) ----------------
#define OFF1_OFF 0
#define OFF2_OFF 4718592
#define OFF3_OFF 5898240
#define R11_OFF  6193152      // 4*64*256*256 f32
#define R21_OFF  22970368     // 4*128*128*128 f32 (n1b+n2b scratch pre-VGG)
#define R31_OFF  31358976     // 4*256*64*64 f32

__device__ __forceinline__ ushort f2bf(float x) {
  union { float f; uint u; } c; c.f = x;
  uint r = c.u + 0x7FFFu + ((c.u >> 16) & 1u);
  return (ushort)(r >> 16);
}
__device__ __forceinline__ float bfval(ushort h) {
  union { uint u; float f; } c; c.u = ((uint)h) << 16;
  return c.f;
}

// ---------------- per-pixel channel L2 normalize -> bf16 hi/lo pos-major
// out per sample: [pos 4096][cc 8][hi 32 | lo 32] ushort (512/pos).
__global__ __launch_bounds__(256)
void k_normalize(const float* __restrict__ f1, const float* __restrict__ f2,
                 ushort* __restrict__ n1b, ushort* __restrict__ n2b) {
  __shared__ uint ldsu[64 * 256];
  float* red = (float*)ldsu;
  float* inv = (float*)ldsu + 256;
  const int t = threadIdx.x, x = t & 63, cg = t >> 6;
  const int h = blockIdx.x, b = blockIdx.y;
  const float* in = blockIdx.z ? f2 : f1;
  ushort* op = blockIdx.z ? n2b : n1b;
  const size_t base = (size_t)b * 256 * 4096 + (size_t)h * 64 + x;
  float vals[64];
  float s = 0.f;
  #pragma unroll
  for (int ci = 0; ci < 64; ++ci) {
    float v = in[base + (size_t)(cg * 64 + ci) * 4096];
    vals[ci] = v;
    s = fmaf(v, v, s);
  }
  red[t] = s;
  __syncthreads();
  if (t < 64) {
    float tot = red[t] + red[64 + t] + red[128 + t] + red[192 + t];
    inv[t] = 1.0f / fmaxf(sqrtf(tot), 1e-12f);
  }
  __syncthreads();
  const float iv = inv[x];
  __syncthreads();
  #pragma unroll
  for (int j = 0; j < 32; ++j) {
    float v0 = vals[2 * j] * iv, v1 = vals[2 * j + 1] * iv;
    ushort h0 = f2bf(v0), h1 = f2bf(v1);
    ushort l0 = f2bf(v0 - bfval(h0)), l1 = f2bf(v1 - bfval(h1));
    int cc = (cg << 1) + (j >> 4);
    int i = j & 15;
    int qh = cc * 32 + i, ql = cc * 32 + 16 + i;
    ldsu[x * 256 + (qh ^ (x & 31))] = (uint)h0 | ((uint)h1 << 16);
    ldsu[x * 256 + (ql ^ (x & 31))] = (uint)l0 | ((uint)l1 << 16);
  }
  __syncthreads();
  uint* og = (uint*)(op + ((size_t)b * 4096 + h * 64) * 512);
  #pragma unroll
  for (int it = 0; it < 64; ++it) {
    int idx = it * 256 + t;
    int p = idx >> 8, q = idx & 255;
    og[idx] = ldsu[p * 256 + (q ^ (p & 31))];
  }
}

// ---------------- pixel-correlation GEMM (MFMA bf16x3): P = A^T B -----
// batched z=4; reg-prefetch pipeline (issue-early / ds_write-late).
__global__ __launch_bounds__(256)
void k_pgemm_mfma(const ushort* __restrict__ Ab0, const ushort* __restrict__ Bb0,
                  float* __restrict__ P0) {
  __shared__ __align__(16) ushort As[128 * 64];
  __shared__ __align__(16) ushort Bs[128 * 64];
  const int t = threadIdx.x;
  const int bz = blockIdx.z;
  const ushort* Ab = Ab0 + (size_t)bz * 2097152;
  const ushort* Bb = Bb0 + (size_t)bz * 2097152;
  float* P = P0 + (size_t)bz * 16777216;
  const int u0 = blockIdx.y * 128, v0 = blockIdx.x * 128;
  const int lane = t & 63, wv = t >> 6;
  const int wm = wv >> 1, wn = wv & 1;
  const int lr = lane & 15, lk = lane >> 4;
  int rowv[4], slotv[4];
  #pragma unroll
  for (int i = 0; i < 4; ++i) { int e = t + i * 256; rowv[i] = e >> 3; slotv[i] = e & 7; }
  s16x8 ra[4], rb[4];
  #pragma unroll
  for (int i = 0; i < 4; ++i) {
    ra[i] = *(const s16x8*)(Ab + ((size_t)(u0 + rowv[i])) * 512 + slotv[i] * 8);
    rb[i] = *(const s16x8*)(Bb + ((size_t)(v0 + rowv[i])) * 512 + slotv[i] * 8);
  }
  f32x4 acc[4][4];
  #pragma unroll
  for (int mt = 0; mt < 4; ++mt)
    #pragma unroll
    for (int nt = 0; nt < 4; ++nt) {
      f32x4 z = {0.f, 0.f, 0.f, 0.f};
      acc[mt][nt] = z;
    }

  #pragma unroll 1
  for (int cc = 0; cc < 8; ++cc) {
    __syncthreads();
    #pragma unroll
    for (int i = 0; i < 4; ++i) {
      *(s16x8*)(As + ((rowv[i] << 3) + (slotv[i] ^ (rowv[i] & 7))) * 8) = ra[i];
      *(s16x8*)(Bs + ((rowv[i] << 3) + (slotv[i] ^ (rowv[i] & 7))) * 8) = rb[i];
    }
    __syncthreads();
    if (cc < 7) {
      #pragma unroll
      for (int i = 0; i < 4; ++i) {
        ra[i] = *(const s16x8*)(Ab + ((size_t)(u0 + rowv[i])) * 512 + (cc + 1) * 64 + slotv[i] * 8);
        rb[i] = *(const s16x8*)(Bb + ((size_t)(v0 + rowv[i])) * 512 + (cc + 1) * 64 + slotv[i] * 8);
      }
    }
    s16x8 ah[4], al[4], bh[4], bl[4];
    #pragma unroll
    for (int mt = 0; mt < 4; ++mt) {
      int row = wm * 64 + mt * 16 + lr;
      ah[mt] = *(const s16x8*)(As + ((row << 3) + (lk ^ (row & 7))) * 8);
      al[mt] = *(const s16x8*)(As + ((row << 3) + ((4 + lk) ^ (row & 7))) * 8);
    }
    #pragma unroll
    for (int nt = 0; nt < 4; ++nt) {
      int row = wn * 64 + nt * 16 + lr;
      bh[nt] = *(const s16x8*)(Bs + ((row << 3) + (lk ^ (row & 7))) * 8);
      bl[nt] = *(const s16x8*)(Bs + ((row << 3) + ((4 + lk) ^ (row & 7))) * 8);
    }
    #pragma unroll
    for (int mt = 0; mt < 4; ++mt)
      #pragma unroll
      for (int nt = 0; nt < 4; ++nt) {
        acc[mt][nt] = __builtin_amdgcn_mfma_f32_16x16x32_bf16(al[mt], bh[nt], acc[mt][nt], 0, 0, 0);
        acc[mt][nt] = __builtin_amdgcn_mfma_f32_16x16x32_bf16(ah[mt], bl[nt], acc[mt][nt], 0, 0, 0);
        acc[mt][nt] = __builtin_amdgcn_mfma_f32_16x16x32_bf16(ah[mt], bh[nt], acc[mt][nt], 0, 0, 0);
      }
  }
  #pragma unroll
  for (int mt = 0; mt < 4; ++mt)
    #pragma unroll
    for (int nt = 0; nt < 4; ++nt) {
      #pragma unroll
      for (int r = 0; r < 4; ++r)
        P[(size_t)(u0 + wm * 64 + mt * 16 + lk * 4 + r) * 4096 +
          v0 + wn * 64 + nt * 16 + lr] = acc[mt][nt][r];
    }
}

// ---------------- 9-tap diagonal sum + per-row partial argmax (z=4) ----
__global__ __launch_bounds__(256)
void k_corr(const float* __restrict__ P0, float* __restrict__ pv0,
            int* __restrict__ pi0) {
  __shared__ float lds[3 * 64 * 65];
  __shared__ float rv[256];
  __shared__ int   ri[256];
  const int t = threadIdx.x;
  const int qy = blockIdx.x, py = blockIdx.y, bz = blockIdx.z;
  const float* P = P0 + (size_t)bz * 16777216;
  float* pv = pv0 + (size_t)bz * 238328;
  int*   pi = pi0 + (size_t)bz * 238328;
  #pragma unroll
  for (int i = 0; i < 12; ++i) {
    int e = t + i * 256;
    int blk = e >> 10, rem = e & 1023;
    int ux = rem >> 4, v4 = (rem & 15) << 2;
    const float4 src = *(const float4*)(
        P + ((size_t)((py + blk) * 64 + ux)) * 4096 + (qy + blk) * 64 + v4);
    float* d = lds + blk * 4160 + ux * 65 + v4;
    d[0] = src.x; d[1] = src.y; d[2] = src.z; d[3] = src.w;
  }
  __syncthreads();
  const int px = t & 63, qg = t >> 6;
  float bv = -3.4e38f; int bq = 0;
  if (px < 62) {
    const int q0 = qg * 16;
    const int nq = (qg < 3) ? 16 : 14;
    const float* base = lds + px * 65 + q0;
    for (int l = 0; l < nq; ++l) {
      float s = 0.f;
      #pragma unroll
      for (int di = 0; di < 3; ++di)
        #pragma unroll
        for (int dj = 0; dj < 3; ++dj)
          s += base[di * 4160 + dj * 66 + l];
      if (s > bv) { bv = s; bq = q0 + l; }
    }
  }
  rv[t] = bv; ri[t] = bq;
  __syncthreads();
  if (t < 62) {
    float v = rv[t]; int q = ri[t];
    #pragma unroll
    for (int g = 1; g < 4; ++g) {
      float v2 = rv[g * 64 + t];
      if (v2 > v) { v = v2; q = ri[g * 64 + t]; }
    }
    const int n = py * 62 + t;
    pv[(size_t)n * 62 + qy] = v;
    pi[(size_t)n * 62 + qy] = qy * 62 + q;
  }
}

// ---------------- final argmax over the 62 qy partials ---------------
__global__ void k_argmax(const float* __restrict__ pv, const int* __restrict__ pi,
                         int* __restrict__ idxf) {
  int tid = blockIdx.x * 256 + threadIdx.x;
  if (tid >= 4 * 3844) return;
  const float* v = pv + (size_t)tid * 62;
  const int*  ii = pi + (size_t)tid * 62;
  float bv = v[0]; int bi = ii[0];
  for (int q = 1; q < 62; ++q) {
    float x = v[q];
    if (x > bv) { bv = x; bi = ii[q]; }
  }
  idxf[tid] = bi;
}

// ---------------- flow pyramid + 9 shifts ----------------------------
__global__ void k_flow(const int* __restrict__ idxf, float* __restrict__ out,
                       int Ho, int lg) {
  int gid = blockIdx.x * 256 + threadIdx.x;
  const int total = 4 * 9 * Ho * Ho;
  if (gid >= total) return;
  const int x = gid % Ho;
  const int y = (gid / Ho) % Ho;
  const int s = (gid / (Ho * Ho)) % 9;
  const int b = gid / (Ho * Ho * 9);
  const int i = s / 3, j = s % 3;
  const int sc = 1 << lg;
  const int yy = y - i * sc, xx = x - j * sc;
  float fw = 0.f, fh = 0.f;
  if (yy >= 0 && xx >= 0) {
    const int r = yy >> lg, c = xx >> lg;
    if (r < 62 && c < 62) {
      const int id = idxf[b * 3844 + r * 62 + c];
      fw = (float)((id % 62 - c) * sc);
      fh = (float)((id / 62 - r) * sc);
    }
  }
  float2 o = {fw, fh};
  *(float2*)(out + (size_t)gid * 2) = o;
}

// ---------------- merged weight prep: all 4 conv weights --------------
__global__ void k_wprep_all(const float* __restrict__ w12, const float* __restrict__ w21,
                            const float* __restrict__ w22, const float* __restrict__ w31,
                            ushort* __restrict__ o12, ushort* __restrict__ o21,
                            ushort* __restrict__ o22, ushort* __restrict__ o31) {
  int gid = blockIdx.x * 256 + threadIdx.x;
  const float* w; ushort* o; int CIN, rel;
  if (gid < 36864)        { w = w12; o = o12; CIN = 64;  rel = gid; }
  else if (gid < 110592)  { w = w21; o = o21; CIN = 64;  rel = gid - 36864; }
  else if (gid < 258048)  { w = w22; o = o22; CIN = 128; rel = gid - 110592; }
  else if (gid < 552960)  { w = w31; o = o31; CIN = 128; rel = gid - 258048; }
  else return;
  const int NC = CIN >> 5;
  int wi = rel & 31;
  int r = rel >> 5;
  int cc = r % NC; r /= NC;
  int tap = r % 9;
  int oc = r / 9;
  int ci = cc * 32 + wi;
  float x = w[((size_t)oc * CIN + ci) * 9 + tap];
  ushort h = f2bf(x);
  ushort l = f2bf(x - bfval(h));
  size_t base = (((size_t)(oc * 9 + tap) * NC + cc) << 6) + wi;
  o[base] = h;
  o[base + 32] = l;
}

// ---------------- conv1_1 (batched y): 3->64, fused input norm --------
__global__ __launch_bounds__(256)
void k_conv11(const float* __restrict__ img0, const float* __restrict__ w,
              const float* __restrict__ bias, float* __restrict__ outF0,
              ushort* __restrict__ outB0) {
  __shared__ float wl[1728];
  __shared__ float bl[64];
  const int t = threadIdx.x;
  const int b = blockIdx.y;
  const float* img = img0 + (size_t)b * 3 * 65536;
  float* outF = outF0 + (size_t)b * 64 * 65536;
  ushort* outB = outB0 + (size_t)b * 8388608;
  for (int i = t; i < 1728; i += 256) wl[i] = w[i];
  if (t < 64) bl[t] = bias[t];
  __syncthreads();
  const int x = t, y = blockIdx.x;
  const float mean[3] = {0.485f, 0.456f, 0.406f};
  const float stdv[3] = {0.229f, 0.224f, 0.225f};
  float v[27];
  #pragma unroll
  for (int c = 0; c < 3; ++c)
    #pragma unroll
    for (int dy = 0; dy < 3; ++dy)
      #pragma unroll
      for (int dx = 0; dx < 3; ++dx) {
        int iy = y + dy - 1, ix = x + dx - 1;
        float val = 0.f;
        if (iy >= 0 && iy < 256 && ix >= 0 && ix < 256)
          val = (img[((size_t)c * 256 + iy) * 256 + ix] - mean[c]) / stdv[c];
        v[c * 9 + dy * 3 + dx] = val;
      }
  float ov[64];
  #pragma unroll 4
  for (int oc = 0; oc < 64; ++oc) {
    float a = bl[oc];
    #pragma unroll
    for (int k = 0; k < 27; ++k) a = fmaf(wl[oc * 27 + k], v[k], a);
    a = fmaxf(a, 0.f);
    ov[oc] = a;
    outF[((size_t)oc * 256 + y) * 256 + x] = a;
  }
  uint* ob = (uint*)(outB + ((((size_t)y) * 256 + x) << 7));
  #pragma unroll
  for (int cc = 0; cc < 2; ++cc)
    #pragma unroll
    for (int i = 0; i < 16; ++i) {
      float v0 = ov[cc * 32 + 2 * i], v1 = ov[cc * 32 + 2 * i + 1];
      ushort h0 = f2bf(v0), h1 = f2bf(v1);
      ushort l0 = f2bf(v0 - bfval(h0)), l1 = f2bf(v1 - bfval(h1));
      ob[cc * 32 + i] = (uint)h0 | ((uint)h1 << 16);
      ob[cc * 32 + 16 + i] = (uint)l0 | ((uint)l1 << 16);
    }
}

// ---------------- MFMA 3x3 conv, bf16x3, batched z --------------------
template <int CIN, bool POOL, bool WB16>
__global__ __launch_bounds__(256)
void k_mconv(const ushort* __restrict__ inb, const ushort* __restrict__ wB,
             const float* __restrict__ bias, float* __restrict__ outF,
             ushort* __restrict__ outB, int H, int W, int Cout,
             int inStride, int fStride, int bStride) {
  __shared__ __align__(16) char lds_raw[33792];
  ushort* As = (ushort*)lds_raw;
  float*  sm = (float*)lds_raw;
  const int t = threadIdx.x;
  const int bz = blockIdx.z;
  inb += (size_t)bz * inStride;
  outF += (size_t)bz * fStride;
  outB += (size_t)bz * bStride;
  const int xtiles = W >> 6;
  const int xt = blockIdx.x % xtiles;
  const int yp = blockIdx.x / xtiles;
  const int x0 = xt << 6, y0 = yp << 1;
  const int ocb = blockIdx.y << 6;
  const int lane = t & 63, wv = t >> 6;
  const int wm = wv >> 1, wn = wv & 1;
  const int lr = lane & 15, lk = lane >> 4;
  constexpr int NC = CIN / 32;

  f32x4 acc[4][2];
  #pragma unroll
  for (int mr = 0; mr < 4; ++mr)
    #pragma unroll
    for (int n = 0; n < 2; ++n) {
      f32x4 z = {0.f, 0.f, 0.f, 0.f};
      acc[mr][n] = z;
    }

  #pragma unroll 1
  for (int cc = 0; cc < NC; ++cc) {
    __syncthreads();
    #pragma unroll
    for (int i = 0; i < 9; ++i) {
      int e = t + i * 256;
      if (e < 2112) {
        int pos = e >> 3, cig = e & 7;
        int hy = pos / 66, hx = pos - hy * 66;
        int gy = y0 + hy - 1, gx = x0 + hx - 1;
        s16x8 v = {0, 0, 0, 0, 0, 0, 0, 0};
        if (gy >= 0 && gy < H && gx >= 0 && gx < W)
          v = *(const s16x8*)(inb + ((size_t)gy * W + gx) * (CIN * 2) +
                              cc * 64 + cig * 8);
        *(s16x8*)(As + ((pos << 3) + (cig ^ (pos & 7))) * 8) = v;
      }
    }
    __syncthreads();
    #pragma unroll 3
    for (int tap = 0; tap < 9; ++tap) {
      const int dy = tap / 3, dx = tap % 3;
      s16x8 bh[2], blo[2];
      #pragma unroll
      for (int n = 0; n < 2; ++n) {
        const ushort* wp =
            wB + (((size_t)(ocb + wn * 32 + n * 16 + lr) * 9 + tap) * NC + cc) * 64 +
            lk * 8;
        bh[n]  = *(const s16x8*)wp;
        blo[n] = *(const s16x8*)(wp + 32);
      }
      #pragma unroll
      for (int mr = 0; mr < 4; ++mr) {
        const int pos = (wm + dy) * 66 + mr * 16 + lr + dx;
        s16x8 ah = *(const s16x8*)(As + ((pos << 3) + (lk ^ (pos & 7))) * 8);
        s16x8 al = *(const s16x8*)(As + ((pos << 3) + ((4 + lk) ^ (pos & 7))) * 8);
        #pragma unroll
        for (int n = 0; n < 2; ++n) {
          acc[mr][n] = __builtin_amdgcn_mfma_f32_16x16x32_bf16(al, bh[n], acc[mr][n], 0, 0, 0);
          acc[mr][n] = __builtin_amdgcn_mfma_f32_16x16x32_bf16(ah, blo[n], acc[mr][n], 0, 0, 0);
          acc[mr][n] = __builtin_amdgcn_mfma_f32_16x16x32_bf16(ah, bh[n], acc[mr][n], 0, 0, 0);
        }
      }
    }
  }
  __syncthreads();
  #pragma unroll
  for (int mr = 0; mr < 4; ++mr)
    #pragma unroll
    for (int n = 0; n < 2; ++n) {
      const int oc = wn * 32 + n * 16 + lr;
      const float bs = bias[ocb + oc];
      #pragma unroll
      for (int r = 0; r < 4; ++r)
        sm[(wm * 64 + mr * 16 + lk * 4 + r) * 65 + oc] =
            fmaxf(acc[mr][n][r] + bs, 0.f);
    }
  __syncthreads();
  if (POOL) {
    const int Wo = W >> 1;
    #pragma unroll
    for (int i = 0; i < 4; ++i) {
      int e = t + i * 256;
      int op = e & 31, xo = e >> 5;
      int oc0 = op * 2;
      float m0 = fmaxf(fmaxf(sm[(xo * 2) * 65 + oc0], sm[(xo * 2 + 1) * 65 + oc0]),
                       fmaxf(sm[(64 + xo * 2) * 65 + oc0], sm[(64 + xo * 2 + 1) * 65 + oc0]));
      float m1 = fmaxf(fmaxf(sm[(xo * 2) * 65 + oc0 + 1], sm[(xo * 2 + 1) * 65 + oc0 + 1]),
                       fmaxf(sm[(64 + xo * 2) * 65 + oc0 + 1], sm[(64 + xo * 2 + 1) * 65 + oc0 + 1]));
      ushort h0 = f2bf(m0), h1 = f2bf(m1);
      ushort l0 = f2bf(m0 - bfval(h0)), l1 = f2bf(m1 - bfval(h1));
      int cg = ocb + oc0;
      size_t pos = (size_t)yp * Wo + (x0 >> 1) + xo;
      size_t base = pos * (size_t)(2 * Cout) + ((size_t)(cg >> 5) << 6) + (cg & 31);
      uint* ob = (uint*)outB;
      ob[base >> 1] = (uint)h0 | ((uint)h1 << 16);
      ob[(base + 32) >> 1] = (uint)l0 | ((uint)l1 << 16);
    }
  } else {
    #pragma unroll
    for (int i = 0; i < 32; ++i) {
      int e = t + i * 256;
      int oc = e >> 7, sp = e & 127;
      outF[((size_t)(ocb + oc) * H + y0 + (sp >> 6)) * W + x0 + (sp & 63)] =
          sm[sp * 65 + oc];
    }
    if (WB16) {
      #pragma unroll
      for (int i = 0; i < 16; ++i) {
        int e = t + i * 256;
        int op = e & 31, sp = e >> 5;
        int oc0 = op * 2;
        float v0 = sm[sp * 65 + oc0], v1 = sm[sp * 65 + oc0 + 1];
        ushort h0 = f2bf(v0), h1 = f2bf(v1);
        ushort l0 = f2bf(v0 - bfval(h0)), l1 = f2bf(v1 - bfval(h1));
        int cg = ocb + oc0;
        size_t pos = ((size_t)(y0 + (sp >> 6))) * W + x0 + (sp & 63);
        size_t base = pos * (size_t)(2 * Cout) + ((size_t)(cg >> 5) << 6) + (cg & 31);
        uint* ob = (uint*)outB;
        ob[base >> 1] = (uint)h0 | ((uint)h1 << 16);
        ob[(base + 32) >> 1] = (uint)l0 | ((uint)l1 << 16);
      }
    }
  }
}

// ---------------------------------------------------------------------
extern "C" void kernel_launch(void* const* d_in, const int* in_sizes, int n_in,
                              void* d_out, int out_size, void* d_ws, size_t ws_size,
                              hipStream_t stream) {
  const float* df1 = (const float*)d_in[0];
  const float* df2 = (const float*)d_in[1];
  const float* img = (const float*)d_in[2];
  const float* w11 = (const float*)d_in[3];
  const float* b11 = (const float*)d_in[4];
  const float* w12 = (const float*)d_in[5];
  const float* b12 = (const float*)d_in[6];
  const float* w21 = (const float*)d_in[7];
  const float* b21 = (const float*)d_in[8];
  const float* w22 = (const float*)d_in[9];
  const float* b22 = (const float*)d_in[10];
  const float* w31 = (const float*)d_in[11];
  const float* b31 = (const float*)d_in[12];
  float* out = (float*)d_out;

  // ---- d_ws layout (ws_size = 4*out_nbytes ≈ 542 MiB; we use ~273 MB):
  // [0, 2.3 MB): idxf + bf16 hi/lo weights
  // [4 MiB, 4 MiB + 268.4 MB): P[4] f32; VGG bf16 scratch overlays P later.
  int* idxf = (int*)d_ws;
  ushort* w12b = (ushort*)(idxf + 15376);
  ushort* w21b = w12b + 73728;
  ushort* w22b = w21b + 147456;
  ushort* w31b = w22b + 294912;
  float* P4 = (float*)((char*)d_ws + (size_t)(4 << 20));
  // VGG scratch overlaying P4 (P dead after k_corr):
  ushort* a11s = (ushort*)P4;            // 4 x 8,388,608
  ushort* p1bs = a11s + 33554432;        // 4 x 2,097,152
  ushort* a21s = p1bs + 8388608;         // 4 x 4,194,304
  ushort* p2bs = a21s + 16777216;        // 4 x 1,048,576

  // ---- d_out overlays (dead before real outputs land)
  ushort* n1b = (ushort*)(out + R21_OFF);   // 2 x 16.8 MB = exactly R21
  ushort* n2b = n1b + 8388608;
  float* pv = out + OFF1_OFF;
  int*   pi = (int*)(out + OFF1_OFF + 953312);

  k_normalize<<<dim3(64, 4, 2), 256, 0, stream>>>(df1, df2, n1b, n2b);
  k_wprep_all<<<2160, 256, 0, stream>>>(w12, w21, w22, w31, w12b, w21b, w22b, w31b);

  k_pgemm_mfma<<<dim3(32, 32, 4), 256, 0, stream>>>(n1b, n2b, P4);
  k_corr<<<dim3(62, 62, 4), 256, 0, stream>>>(P4, pv, pi);
  k_argmax<<<61, 256, 0, stream>>>(pv, pi, idxf);

  // ---- VGG chain, batched over samples (scratch overlays dead P4)
  k_conv11<<<dim3(256, 4), 256, 0, stream>>>(img, w11, b11, out + R11_OFF, a11s);
  k_mconv<64, true, false><<<dim3(512, 1, 4), 256, 0, stream>>>(
      a11s, w12b, b12, nullptr, p1bs, 256, 256, 64, 8388608, 0, 2097152);
  k_mconv<64, false, true><<<dim3(128, 2, 4), 256, 0, stream>>>(
      p1bs, w21b, b21, out + R21_OFF, a21s, 128, 128, 128, 2097152, 2097152, 4194304);
  k_mconv<128, true, false><<<dim3(128, 2, 4), 256, 0, stream>>>(
      a21s, w22b, b22, nullptr, p2bs, 128, 128, 128, 4194304, 0, 1048576);
  k_mconv<128, false, false><<<dim3(32, 4, 4), 256, 0, stream>>>(
      p2bs, w31b, b31, out + R31_OFF, nullptr, 64, 64, 256, 1048576, 1048576, 0);

  // ---- offset pyramids last (overwrite pv/pi region)
  k_flow<<<(4 * 9 * 256 * 256 + 255) / 256, 256, 0, stream>>>(idxf, out + OFF1_OFF, 256, 2);
  k_flow<<<(4 * 9 * 128 * 128 + 255) / 256, 256, 0, stream>>>(idxf, out + OFF2_OFF, 128, 1);
  k_flow<<<(4 * 9 * 64 * 64 + 255) / 256, 256, 0, stream>>>(idxf, out + OFF3_OFF, 64, 0);
}

// Round 5
// 456.894 us; speedup vs baseline: 4.6106x; 1.3557x over previous
//
#include <hip/hip_runtime.h>

typedef __attribute__((ext_vector_type(4))) float f32x4;
typedef __attribute__((ext_vector_type(8))) short s16x8;

// ---------------- output layout (float element offsets) ----------------
#define OFF1_OFF 0
#define OFF2_OFF 4718592
#define OFF3_OFF 5898240
#define R11_OFF  6193152      // 4*64*256*256 f32
#define R21_OFF  22970368     // 4*128*128*128 f32 (n1b+n2b scratch pre-VGG)
#define R31_OFF  31358976     // 4*256*64*64 f32

__device__ __forceinline__ ushort f2bf(float x) {
  union { float f; uint u; } c; c.f = x;
  uint r = c.u + 0x7FFFu + ((c.u >> 16) & 1u);
  return (ushort)(r >> 16);
}
__device__ __forceinline__ float bfval(ushort h) {
  union { uint u; float f; } c; c.u = ((uint)h) << 16;
  return c.f;
}

// ---------------- per-pixel channel L2 normalize -> bf16 hi/lo pos-major
// out per sample: [pos 4096][cc 8][hi 32 | lo 32] ushort (512/pos).
__global__ __launch_bounds__(256)
void k_normalize(const float* __restrict__ f1, const float* __restrict__ f2,
                 ushort* __restrict__ n1b, ushort* __restrict__ n2b) {
  __shared__ uint ldsu[64 * 256];
  float* red = (float*)ldsu;
  float* inv = (float*)ldsu + 256;
  const int t = threadIdx.x, x = t & 63, cg = t >> 6;
  const int h = blockIdx.x, b = blockIdx.y;
  const float* in = blockIdx.z ? f2 : f1;
  ushort* op = blockIdx.z ? n2b : n1b;
  const size_t base = (size_t)b * 256 * 4096 + (size_t)h * 64 + x;
  float vals[64];
  float s = 0.f;
  #pragma unroll
  for (int ci = 0; ci < 64; ++ci) {
    float v = in[base + (size_t)(cg * 64 + ci) * 4096];
    vals[ci] = v;
    s = fmaf(v, v, s);
  }
  red[t] = s;
  __syncthreads();
  if (t < 64) {
    float tot = red[t] + red[64 + t] + red[128 + t] + red[192 + t];
    inv[t] = 1.0f / fmaxf(sqrtf(tot), 1e-12f);
  }
  __syncthreads();
  const float iv = inv[x];
  __syncthreads();
  #pragma unroll
  for (int j = 0; j < 32; ++j) {
    float v0 = vals[2 * j] * iv, v1 = vals[2 * j + 1] * iv;
    ushort h0 = f2bf(v0), h1 = f2bf(v1);
    ushort l0 = f2bf(v0 - bfval(h0)), l1 = f2bf(v1 - bfval(h1));
    int cc = (cg << 1) + (j >> 4);
    int i = j & 15;
    int qh = cc * 32 + i, ql = cc * 32 + 16 + i;
    ldsu[x * 256 + (qh ^ (x & 31))] = (uint)h0 | ((uint)h1 << 16);
    ldsu[x * 256 + (ql ^ (x & 31))] = (uint)l0 | ((uint)l1 << 16);
  }
  __syncthreads();
  uint* og = (uint*)(op + ((size_t)b * 4096 + h * 64) * 512);
  #pragma unroll
  for (int it = 0; it < 64; ++it) {
    int idx = it * 256 + t;
    int p = idx >> 8, q = idx & 255;
    og[idx] = ldsu[p * 256 + (q ^ (p & 31))];
  }
}

// ---------------- pixel-correlation GEMM (MFMA bf16x3): P = A^T B -----
// batched z=4; P written PLANE-MAJOR: P[(uy*64+vy)*4096 + ux*64 + vx].
__global__ __launch_bounds__(256)
void k_pgemm_mfma(const ushort* __restrict__ Ab0, const ushort* __restrict__ Bb0,
                  float* __restrict__ P0) {
  __shared__ __align__(16) ushort As[128 * 64];
  __shared__ __align__(16) ushort Bs[128 * 64];
  const int t = threadIdx.x;
  const int bz = blockIdx.z;
  const ushort* Ab = Ab0 + (size_t)bz * 2097152;
  const ushort* Bb = Bb0 + (size_t)bz * 2097152;
  float* P = P0 + (size_t)bz * 16777216;
  const int u0 = blockIdx.y * 128, v0 = blockIdx.x * 128;
  const int lane = t & 63, wv = t >> 6;
  const int wm = wv >> 1, wn = wv & 1;
  const int lr = lane & 15, lk = lane >> 4;
  int rowv[4], slotv[4];
  #pragma unroll
  for (int i = 0; i < 4; ++i) { int e = t + i * 256; rowv[i] = e >> 3; slotv[i] = e & 7; }
  s16x8 ra[4], rb[4];
  #pragma unroll
  for (int i = 0; i < 4; ++i) {
    ra[i] = *(const s16x8*)(Ab + ((size_t)(u0 + rowv[i])) * 512 + slotv[i] * 8);
    rb[i] = *(const s16x8*)(Bb + ((size_t)(v0 + rowv[i])) * 512 + slotv[i] * 8);
  }
  f32x4 acc[4][4];
  #pragma unroll
  for (int mt = 0; mt < 4; ++mt)
    #pragma unroll
    for (int nt = 0; nt < 4; ++nt) {
      f32x4 z = {0.f, 0.f, 0.f, 0.f};
      acc[mt][nt] = z;
    }

  #pragma unroll 1
  for (int cc = 0; cc < 8; ++cc) {
    __syncthreads();
    #pragma unroll
    for (int i = 0; i < 4; ++i) {
      *(s16x8*)(As + ((rowv[i] << 3) + (slotv[i] ^ (rowv[i] & 7))) * 8) = ra[i];
      *(s16x8*)(Bs + ((rowv[i] << 3) + (slotv[i] ^ (rowv[i] & 7))) * 8) = rb[i];
    }
    __syncthreads();
    if (cc < 7) {
      #pragma unroll
      for (int i = 0; i < 4; ++i) {
        ra[i] = *(const s16x8*)(Ab + ((size_t)(u0 + rowv[i])) * 512 + (cc + 1) * 64 + slotv[i] * 8);
        rb[i] = *(const s16x8*)(Bb + ((size_t)(v0 + rowv[i])) * 512 + (cc + 1) * 64 + slotv[i] * 8);
      }
    }
    s16x8 ah[4], al[4], bh[4], bl[4];
    #pragma unroll
    for (int mt = 0; mt < 4; ++mt) {
      int row = wm * 64 + mt * 16 + lr;
      ah[mt] = *(const s16x8*)(As + ((row << 3) + (lk ^ (row & 7))) * 8);
      al[mt] = *(const s16x8*)(As + ((row << 3) + ((4 + lk) ^ (row & 7))) * 8);
    }
    #pragma unroll
    for (int nt = 0; nt < 4; ++nt) {
      int row = wn * 64 + nt * 16 + lr;
      bh[nt] = *(const s16x8*)(Bs + ((row << 3) + (lk ^ (row & 7))) * 8);
      bl[nt] = *(const s16x8*)(Bs + ((row << 3) + ((4 + lk) ^ (row & 7))) * 8);
    }
    #pragma unroll
    for (int mt = 0; mt < 4; ++mt)
      #pragma unroll
      for (int nt = 0; nt < 4; ++nt) {
        acc[mt][nt] = __builtin_amdgcn_mfma_f32_16x16x32_bf16(al[mt], bh[nt], acc[mt][nt], 0, 0, 0);
        acc[mt][nt] = __builtin_amdgcn_mfma_f32_16x16x32_bf16(ah[mt], bl[nt], acc[mt][nt], 0, 0, 0);
        acc[mt][nt] = __builtin_amdgcn_mfma_f32_16x16x32_bf16(ah[mt], bh[nt], acc[mt][nt], 0, 0, 0);
      }
  }
  // plane-major epilogue: each wave owns one 64x64 plane
  const int plane = ((blockIdx.y * 2 + wm) << 6) + blockIdx.x * 2 + wn;
  float* Pp = P + (size_t)plane * 4096;
  #pragma unroll
  for (int mt = 0; mt < 4; ++mt)
    #pragma unroll
    for (int nt = 0; nt < 4; ++nt) {
      #pragma unroll
      for (int r = 0; r < 4; ++r)
        Pp[(mt * 16 + lk * 4 + r) * 64 + nt * 16 + lr] = acc[mt][nt][r];
    }
}

// ---------------- corr v2: separable 9-tap + partial argmax ----------
// 1D grid 15376 (= 8*1922, XCD-swizzled). Per block: planes (py+d, qy+d),
// d=0..2 staged to LDS (swizzled f32x4 slots), T = sum in-place, 3-tap diag.
__global__ __launch_bounds__(256)
void k_corr(const float* __restrict__ P0, float* __restrict__ pv0,
            int* __restrict__ pi0) {
  __shared__ __align__(16) f32x4 Pl[3 * 1024];
  __shared__ float rv[256];
  __shared__ int   ri[256];
  const int t = threadIdx.x;
  const int orig = blockIdx.x;
  const int w = (orig & 7) * 1922 + (orig >> 3);
  const int bz = w / 3844;
  const int r2 = w % 3844;
  const int py = r2 / 62, qy = r2 % 62;
  const float* P = P0 + (size_t)bz * 16777216;
  float* pv = pv0 + (size_t)bz * 238328;
  int*   pi = pi0 + (size_t)bz * 238328;
  // stage 3 planes (16 KB each, contiguous)
  #pragma unroll
  for (int i = 0; i < 12; ++i) {
    int e = t + i * 256;
    int blk = e >> 10, rem = e & 1023;
    int px = rem >> 4, q4 = rem & 15;
    int pidx = (py + blk) * 64 + (qy + blk);
    f32x4 v = *(const f32x4*)(P + (size_t)pidx * 4096 + rem * 4);
    int slot = ((q4 + (px >> 4)) & 15) ^ (px & 15);
    Pl[blk * 1024 + px * 16 + slot] = v;
  }
  __syncthreads();
  // T = Pl0 + Pl1 + Pl2 in-place into Pl[0]
  const int px = t & 63, cg = t >> 6;
  #pragma unroll
  for (int j = 0; j < 4; ++j) {
    int c = cg * 4 + j;
    int slot = ((c + (px >> 4)) & 15) ^ (px & 15);
    int o = px * 16 + slot;
    Pl[o] = Pl[o] + Pl[1024 + o] + Pl[2048 + o];
  }
  __syncthreads();
  float bv = -3.4e38f; int bq = 0;
  if (px < 62) {
    const int q0 = cg * 16;
    const int nq = (cg < 3) ? 16 : 14;
    const int nch = (cg < 3) ? 5 : 4;
    float f[3][20];
    #pragma unroll
    for (int dj = 0; dj < 3; ++dj) {
      const int row = px + dj;
      const int rr = row >> 4, rm = row & 15;
      #pragma unroll
      for (int cc2 = 0; cc2 < 5; ++cc2) {
        if (cc2 < nch) {
          int c = cg * 4 + cc2;
          int slot = ((c + rr) & 15) ^ rm;
          f32x4 v = Pl[row * 16 + slot];
          f[dj][cc2 * 4 + 0] = v[0];
          f[dj][cc2 * 4 + 1] = v[1];
          f[dj][cc2 * 4 + 2] = v[2];
          f[dj][cc2 * 4 + 3] = v[3];
        }
      }
    }
    #pragma unroll
    for (int l = 0; l < 16; ++l) {
      if (l < nq) {
        float s = f[0][l] + f[1][l + 1] + f[2][l + 2];
        if (s > bv) { bv = s; bq = q0 + l; }
      }
    }
  }
  rv[t] = bv; ri[t] = bq;
  __syncthreads();
  if (t < 62) {
    float v = rv[t]; int q = ri[t];
    #pragma unroll
    for (int g = 1; g < 4; ++g) {
      float v2 = rv[g * 64 + t];
      if (v2 > v) { v = v2; q = ri[g * 64 + t]; }
    }
    const int n = py * 62 + t;
    pv[(size_t)n * 62 + qy] = v;
    pi[(size_t)n * 62 + qy] = qy * 62 + q;
  }
}

// ---------------- final argmax over the 62 qy partials ---------------
__global__ void k_argmax(const float* __restrict__ pv, const int* __restrict__ pi,
                         int* __restrict__ idxf) {
  int tid = blockIdx.x * 256 + threadIdx.x;
  if (tid >= 4 * 3844) return;
  const float* v = pv + (size_t)tid * 62;
  const int*  ii = pi + (size_t)tid * 62;
  float bv = v[0]; int bi = ii[0];
  for (int q = 1; q < 62; ++q) {
    float x = v[q];
    if (x > bv) { bv = x; bi = ii[q]; }
  }
  idxf[tid] = bi;
}

// ---------------- flow pyramid + 9 shifts (all 3 levels merged) ------
__global__ void k_flow_all(const int* __restrict__ idxf, float* __restrict__ out) {
  int gid = blockIdx.x * 256 + threadIdx.x;
  int Ho, lg, rel = gid;
  float* o;
  if (gid < 2359296)      { Ho = 256; lg = 2; o = out + OFF1_OFF; }
  else if (gid < 2949120) { Ho = 128; lg = 1; o = out + OFF2_OFF; rel -= 2359296; }
  else if (gid < 3096576) { Ho = 64;  lg = 0; o = out + OFF3_OFF; rel -= 2949120; }
  else return;
  const int x = rel % Ho;
  const int y = (rel / Ho) % Ho;
  const int s = (rel / (Ho * Ho)) % 9;
  const int b = rel / (Ho * Ho * 9);
  const int i = s / 3, j = s % 3;
  const int sc = 1 << lg;
  const int yy = y - i * sc, xx = x - j * sc;
  float fw = 0.f, fh = 0.f;
  if (yy >= 0 && xx >= 0) {
    const int r = yy >> lg, c = xx >> lg;
    if (r < 62 && c < 62) {
      const int id = idxf[b * 3844 + r * 62 + c];
      fw = (float)((id % 62 - c) * sc);
      fh = (float)((id / 62 - r) * sc);
    }
  }
  float2 ov = {fw, fh};
  *(float2*)(o + (size_t)rel * 2) = ov;
}

// ---------------- weight prep: f32 OIHW -> bf16 [oc][tap][ci] --------
__global__ void k_wprep_all(const float* __restrict__ w12, const float* __restrict__ w21,
                            const float* __restrict__ w22, const float* __restrict__ w31,
                            ushort* __restrict__ o12, ushort* __restrict__ o21,
                            ushort* __restrict__ o22, ushort* __restrict__ o31) {
  int gid = blockIdx.x * 256 + threadIdx.x;
  const float* w; ushort* o; int CIN, rel;
  if (gid < 36864)        { w = w12; o = o12; CIN = 64;  rel = gid; }
  else if (gid < 110592)  { w = w21; o = o21; CIN = 64;  rel = gid - 36864; }
  else if (gid < 258048)  { w = w22; o = o22; CIN = 128; rel = gid - 110592; }
  else if (gid < 552960)  { w = w31; o = o31; CIN = 128; rel = gid - 258048; }
  else return;
  int ci = rel % CIN;
  int r = rel / CIN;
  int tap = r % 9;
  int oc = r / 9;
  o[((size_t)oc * 9 + tap) * CIN + ci] = f2bf(w[((size_t)oc * CIN + ci) * 9 + tap]);
}

// ---------------- conv1_1 (batched y): 3->64, fused input norm --------
// outF: r11 f32 NCHW; outB: bf16 NHWC [pos][64]
__global__ __launch_bounds__(256)
void k_conv11(const float* __restrict__ img0, const float* __restrict__ w,
              const float* __restrict__ bias, float* __restrict__ outF0,
              ushort* __restrict__ outB0) {
  __shared__ float wl[1728];
  __shared__ float bl[64];
  const int t = threadIdx.x;
  const int b = blockIdx.y;
  const float* img = img0 + (size_t)b * 3 * 65536;
  float* outF = outF0 + (size_t)b * 64 * 65536;
  ushort* outB = outB0 + (size_t)b * 4194304;
  for (int i = t; i < 1728; i += 256) wl[i] = w[i];
  if (t < 64) bl[t] = bias[t];
  __syncthreads();
  const int x = t, y = blockIdx.x;
  const float mean[3] = {0.485f, 0.456f, 0.406f};
  const float stdv[3] = {0.229f, 0.224f, 0.225f};
  float v[27];
  #pragma unroll
  for (int c = 0; c < 3; ++c)
    #pragma unroll
    for (int dy = 0; dy < 3; ++dy)
      #pragma unroll
      for (int dx = 0; dx < 3; ++dx) {
        int iy = y + dy - 1, ix = x + dx - 1;
        float val = 0.f;
        if (iy >= 0 && iy < 256 && ix >= 0 && ix < 256)
          val = (img[((size_t)c * 256 + iy) * 256 + ix] - mean[c]) / stdv[c];
        v[c * 9 + dy * 3 + dx] = val;
      }
  float ov[64];
  #pragma unroll 4
  for (int oc = 0; oc < 64; ++oc) {
    float a = bl[oc];
    #pragma unroll
    for (int k = 0; k < 27; ++k) a = fmaf(wl[oc * 27 + k], v[k], a);
    a = fmaxf(a, 0.f);
    ov[oc] = a;
    outF[((size_t)oc * 256 + y) * 256 + x] = a;
  }
  uint* ob = (uint*)(outB + ((((size_t)y) * 256 + x) << 6));
  #pragma unroll
  for (int j = 0; j < 32; ++j)
    ob[j] = (uint)f2bf(ov[2 * j]) | ((uint)f2bf(ov[2 * j + 1]) << 16);
}

// ---------------- MFMA 3x3 conv, single-pass bf16, batched z ----------
// in: NHWC bf16 [pos][CIN]; wB: [oc][tap][CIN] bf16.
template <int CIN, bool POOL, bool WB16>
__global__ __launch_bounds__(256)
void k_mconv(const ushort* __restrict__ inb, const ushort* __restrict__ wB,
             const float* __restrict__ bias, float* __restrict__ outF,
             ushort* __restrict__ outB, int H, int W, int Cout,
             int inStride, int fStride, int bStride) {
  __shared__ __align__(16) char lds_raw[33792];
  ushort* As = (ushort*)lds_raw;           // [264 pos][8 slots][8] swizzled
  float*  sm = (float*)lds_raw;            // epilogue [128][65]
  const int t = threadIdx.x;
  const int bz = blockIdx.z;
  inb += (size_t)bz * inStride;
  outF += (size_t)bz * fStride;
  outB += (size_t)bz * bStride;
  const int xtiles = W >> 6;
  const int xt = blockIdx.x % xtiles;
  const int yp = blockIdx.x / xtiles;
  const int x0 = xt << 6, y0 = yp << 1;
  const int ocb = blockIdx.y << 6;
  const int lane = t & 63, wv = t >> 6;
  const int wm = wv >> 1, wn = wv & 1;
  const int lr = lane & 15, lk = lane >> 4;
  constexpr int NC2 = CIN / 64;            // 64-channel chunks

  f32x4 acc[4][2];
  #pragma unroll
  for (int mr = 0; mr < 4; ++mr)
    #pragma unroll
    for (int n = 0; n < 2; ++n) {
      f32x4 z = {0.f, 0.f, 0.f, 0.f};
      acc[mr][n] = z;
    }

  #pragma unroll 1
  for (int cc = 0; cc < NC2; ++cc) {
    __syncthreads();
    #pragma unroll
    for (int i = 0; i < 9; ++i) {
      int e = t + i * 256;
      if (e < 2112) {
        int pos = e >> 3, cig = e & 7;
        int hy = pos / 66, hx = pos - hy * 66;
        int gy = y0 + hy - 1, gx = x0 + hx - 1;
        s16x8 v = {0, 0, 0, 0, 0, 0, 0, 0};
        if (gy >= 0 && gy < H && gx >= 0 && gx < W)
          v = *(const s16x8*)(inb + ((size_t)gy * W + gx) * CIN + cc * 64 + cig * 8);
        *(s16x8*)(As + ((pos << 3) + (cig ^ (pos & 7))) * 8) = v;
      }
    }
    __syncthreads();
    #pragma unroll 3
    for (int tap = 0; tap < 9; ++tap) {
      const int dy = tap / 3, dx = tap % 3;
      s16x8 b0[2], b1[2];
      #pragma unroll
      for (int n = 0; n < 2; ++n) {
        const ushort* wp =
            wB + ((size_t)(ocb + wn * 32 + n * 16 + lr) * 9 + tap) * CIN + cc * 64 + lk * 8;
        b0[n] = *(const s16x8*)wp;
        b1[n] = *(const s16x8*)(wp + 32);
      }
      #pragma unroll
      for (int mr = 0; mr < 4; ++mr) {
        const int pos = (wm + dy) * 66 + mr * 16 + lr + dx;
        s16x8 a0 = *(const s16x8*)(As + ((pos << 3) + (lk ^ (pos & 7))) * 8);
        s16x8 a1 = *(const s16x8*)(As + ((pos << 3) + ((4 + lk) ^ (pos & 7))) * 8);
        #pragma unroll
        for (int n = 0; n < 2; ++n) {
          acc[mr][n] = __builtin_amdgcn_mfma_f32_16x16x32_bf16(a0, b0[n], acc[mr][n], 0, 0, 0);
          acc[mr][n] = __builtin_amdgcn_mfma_f32_16x16x32_bf16(a1, b1[n], acc[mr][n], 0, 0, 0);
        }
      }
    }
  }
  __syncthreads();
  #pragma unroll
  for (int mr = 0; mr < 4; ++mr)
    #pragma unroll
    for (int n = 0; n < 2; ++n) {
      const int oc = wn * 32 + n * 16 + lr;
      const float bs = bias[ocb + oc];
      #pragma unroll
      for (int r = 0; r < 4; ++r)
        sm[(wm * 64 + mr * 16 + lk * 4 + r) * 65 + oc] =
            fmaxf(acc[mr][n][r] + bs, 0.f);
    }
  __syncthreads();
  if (POOL) {
    const int Wo = W >> 1;
    #pragma unroll
    for (int i = 0; i < 4; ++i) {
      int e = t + i * 256;
      int op = e & 31, xo = e >> 5;
      int oc0 = op * 2;
      float m0 = fmaxf(fmaxf(sm[(xo * 2) * 65 + oc0], sm[(xo * 2 + 1) * 65 + oc0]),
                       fmaxf(sm[(64 + xo * 2) * 65 + oc0], sm[(64 + xo * 2 + 1) * 65 + oc0]));
      float m1 = fmaxf(fmaxf(sm[(xo * 2) * 65 + oc0 + 1], sm[(xo * 2 + 1) * 65 + oc0 + 1]),
                       fmaxf(sm[(64 + xo * 2) * 65 + oc0 + 1], sm[(64 + xo * 2 + 1) * 65 + oc0 + 1]));
      size_t pos = (size_t)yp * Wo + (x0 >> 1) + xo;
      ((uint*)outB)[pos * (Cout >> 1) + ((ocb >> 1) + op)] =
          (uint)f2bf(m0) | ((uint)f2bf(m1) << 16);
    }
  } else {
    #pragma unroll
    for (int i = 0; i < 32; ++i) {
      int e = t + i * 256;
      int oc = e >> 7, sp = e & 127;
      outF[((size_t)(ocb + oc) * H + y0 + (sp >> 6)) * W + x0 + (sp & 63)] =
          sm[sp * 65 + oc];
    }
    if (WB16) {
      #pragma unroll
      for (int i = 0; i < 16; ++i) {
        int e = t + i * 256;
        int op = e & 31, sp = e >> 5;
        int oc0 = op * 2;
        float v0 = sm[sp * 65 + oc0], v1 = sm[sp * 65 + oc0 + 1];
        size_t pos = ((size_t)(y0 + (sp >> 6))) * W + x0 + (sp & 63);
        ((uint*)outB)[pos * (Cout >> 1) + ((ocb >> 1) + op)] =
            (uint)f2bf(v0) | ((uint)f2bf(v1) << 16);
      }
    }
  }
}

// ---------------------------------------------------------------------
extern "C" void kernel_launch(void* const* d_in, const int* in_sizes, int n_in,
                              void* d_out, int out_size, void* d_ws, size_t ws_size,
                              hipStream_t stream) {
  const float* df1 = (const float*)d_in[0];
  const float* df2 = (const float*)d_in[1];
  const float* img = (const float*)d_in[2];
  const float* w11 = (const float*)d_in[3];
  const float* b11 = (const float*)d_in[4];
  const float* w12 = (const float*)d_in[5];
  const float* b12 = (const float*)d_in[6];
  const float* w21 = (const float*)d_in[7];
  const float* b21 = (const float*)d_in[8];
  const float* w22 = (const float*)d_in[9];
  const float* b22 = (const float*)d_in[10];
  const float* w31 = (const float*)d_in[11];
  const float* b31 = (const float*)d_in[12];
  float* out = (float*)d_out;

  // ---- d_ws: [0,1.2MB) idxf + bf16 weights; [4MiB, +268MB) P4 planes /
  // VGG bf16 activations (overlay P4 after corr).
  int* idxf = (int*)d_ws;
  ushort* w12b = (ushort*)(idxf + 15376);     // 36864
  ushort* w21b = w12b + 36864;                // 73728
  ushort* w22b = w21b + 73728;                // 147456
  ushort* w31b = w22b + 147456;               // 294912
  float* P4 = (float*)((char*)d_ws + (size_t)(4 << 20));
  ushort* a11s = (ushort*)P4;                 // 4 x 4,194,304
  ushort* p1bs = a11s + 16777216;             // 4 x 1,048,576
  ushort* a21s = p1bs + 4194304;              // 4 x 2,097,152
  ushort* p2bs = a21s + 8388608;              // 4 x 524,288

  // ---- d_out overlays (dead before real outputs land)
  ushort* n1b = (ushort*)(out + R21_OFF);     // 2 x 16.8 MB = exactly R21
  ushort* n2b = n1b + 8388608;
  float* pv = out + OFF1_OFF;
  int*   pi = (int*)(out + OFF1_OFF + 953312);

  k_normalize<<<dim3(64, 4, 2), 256, 0, stream>>>(df1, df2, n1b, n2b);
  k_wprep_all<<<2160, 256, 0, stream>>>(w12, w21, w22, w31, w12b, w21b, w22b, w31b);

  k_pgemm_mfma<<<dim3(32, 32, 4), 256, 0, stream>>>(n1b, n2b, P4);
  k_corr<<<15376, 256, 0, stream>>>(P4, pv, pi);
  k_argmax<<<61, 256, 0, stream>>>(pv, pi, idxf);

  // ---- VGG chain, batched over samples (bf16 scratch overlays dead P4)
  k_conv11<<<dim3(256, 4), 256, 0, stream>>>(img, w11, b11, out + R11_OFF, a11s);
  k_mconv<64, true, false><<<dim3(512, 1, 4), 256, 0, stream>>>(
      a11s, w12b, b12, nullptr, p1bs, 256, 256, 64, 4194304, 0, 1048576);
  k_mconv<64, false, true><<<dim3(128, 2, 4), 256, 0, stream>>>(
      p1bs, w21b, b21, out + R21_OFF, a21s, 128, 128, 128, 1048576, 2097152, 2097152);
  k_mconv<128, true, false><<<dim3(128, 2, 4), 256, 0, stream>>>(
      a21s, w22b, b22, nullptr, p2bs, 128, 128, 128, 2097152, 0, 524288);
  k_mconv<128, false, false><<<dim3(32, 4, 4), 256, 0, stream>>>(
      p2bs, w31b, b31, out + R31_OFF, nullptr, 64, 64, 256, 524288, 1048576, 0);

  // ---- offset pyramids last (overwrite pv/pi region)
  k_flow_all<<<12096, 256, 0, stream>>>(idxf, out);
}